// Round 5
// baseline (868.465 us; speedup 1.0000x reference)
//
#include <hip/hip_runtime.h>
#include <hip/hip_cooperative_groups.h>
namespace cg = cooperative_groups;

// r19: collapse the serial 8-step recurrence (was ~20 dependent launches,
// ~8us launch+drain overhead each) into ONE cooperative kernel with
// grid.sync() phase barriers: prep (embed+wsplit) -> batched all-7 layer-1
// input convs (gi1 now 7 slots; removed from the serial loop) -> 8x {gates
// phase; conv phase rec1/in2/rec2}. Grid occupancy-clamped <=768 (3/CU @
// 32KB LDS), all phases grid-strided so any clamp stays correct. Head stays
// a separate kernel (48KB LDS). Conv tile / gates math verbatim from r18
// (known-good, absmax 0.0039); one extra __syncthreads at tile end for LDS
// reuse across grid-strided tasks.

typedef _Float16 f16;
typedef _Float16 f16x8 __attribute__((ext_vector_type(8)));
typedef float    f32x4 __attribute__((ext_vector_type(4)));

#define WSTRIDE 442368   // fp32 weight elements per layer: 27*64*256
#define WPT     884736   // halfs per packed tensor: 54*256*64
#define XSP     65536    // halfs per s-slab of h: 512*128
#define HSP     458752   // halfs per nc of h: 7*512*128
#define GPART   262144   // floats per conv partial buffer: 2*512*256

__device__ __forceinline__ float wred_sum(float v) {
    #pragma unroll
    for (int o = 32; o > 0; o >>= 1) v += __shfl_down(v, o, 64);
    return __shfl(v, 0, 64);
}
__device__ __forceinline__ float fsig(float x)  { return 1.f / (1.f + __expf(-x)); }
__device__ __forceinline__ float ftanh(float x) { return 1.f - 2.f / (__expf(2.f*x) + 1.f); }

struct MJob { const f16* x; const f16* w; float* y; };
struct GJob {
    const float* giA; const float* giB;
    const float* ghA; const float* ghB;
    const float* bin; const float* bhb;
    const float* ginw; const float* ginb;
    const float* ghw;  const float* ghb;
    float* cx; f16* h16; int k; int k0;
};
struct MegaArgs {
    const int* code; const int* ncode; const float* emb;
    const float* win; const float* wh;
    const float* bin_; const float* bh;
    const float* gin_w; const float* gin_b;
    const float* gh_w;  const float* gh_b;
    f16* wp; f16* h1; f16* h2;
    float* gi1; float* gi2; float* ghat1; float* ghat2;
    float* cx1; float* cx2;
};

// ---- phase bodies (verbatim r18 logic) ----

__device__ void prep_task(const MegaArgs& A, int task, int t) {
    if (task < 1792) {
        int e = task * 256 + t;          // < 458752
        int ch = e & 63;
        int pos = e >> 6;                // nc*7*512 + s*512 + vox
        int vox = pos & 511;
        int tt = pos >> 9;
        int s = tt % 7, nc = tt / 7;
        int tok = (s < 5) ? A.code[(nc*5 + s)*512 + vox]
                          : A.ncode[(nc*3 + (s-5))*512 + vox];
        float x = A.emb[tok*64 + ch];
        f16 hi = (f16)x;
        A.h1[(size_t)pos*128 + ch]      = hi;
        A.h1[(size_t)pos*128 + 64 + ch] = (f16)(x - (float)hi);
    } else {
        // pack: src [27][64 ci][256 co] fp32 -> per K-atom (tap, ci-half)
        // [54][256 co][8 chunks][8] f16; hi chunk j at (j ^ (co&7)), lo at
        // ((4+j) ^ (co&7)); values x64. Order: win0, wh0, win1, wh1.
        int b = task - 1792;             // 108 = 4 tensors * 27 taps
        int tensor = b / 27, tap = b % 27;
        const float* src = ((tensor & 1) ? A.wh : A.win)
                         + (tensor >> 1) * WSTRIDE + tap * 16384;
        int co = t;
        int sw = co & 7;
        #pragma unroll
        for (int hs = 0; hs < 2; ++hs) {
            f16* dst = A.wp + (((size_t)tensor*27 + tap)*2 + hs)*16384 + co*64;
            #pragma unroll
            for (int j = 0; j < 4; ++j) {
                f16x8 hi8, lo8;
                #pragma unroll
                for (int m = 0; m < 8; ++m) {
                    float w = src[(hs*32 + j*8 + m)*256 + co] * 64.f;
                    f16 hv = (f16)w;
                    hi8[m] = hv;
                    lo8[m] = (f16)(w - (float)hv);
                }
                *(f16x8*)(dst + ((j     ^ sw))*8) = hi8;
                *(f16x8*)(dst + (((4+j) ^ sw))*8) = lo8;
            }
        }
    }
}

// One conv tile: 32-vox a-half x 64 co, K-atoms split over 8 groups
// (kb*4+wid). 3-segment hi/lo f16 MFMA, partial written to y + kb*GPART.
__device__ void conv_tile(const MJob& J, int bx, int t, float4* smem) {
    f16* wbuf = (f16*)smem;
    const int cog = bx & 3, u = (bx >> 2) & 7, slab = (bx >> 5) & 1;
    const int ah = (bx >> 6) & 1, kb = bx >> 7;
    const int wid = t >> 6, l = t & 63;
    const int lv = (l >> 3) & 1, lw = l & 7, khi = l >> 4;

    const int gid = kb*4 + wid;
    const int g0  = (gid < 6) ? gid*7 : 42 + (gid - 6)*6;
    const int cnt = (gid < 6) ? 7 : 6;

    const f16* xbase = J.x + (size_t)slab * HSP;
    const f16* wjob  = J.w + (size_t)cog * 4096;      // + atom*16384
    f16* wmine = wbuf + wid * 4096;                   // 8KB, single-buffered

    f16x8 wreg[8];
    auto wload = [&](int k) {
        const f16* src = wjob + (size_t)k * 16384 + l * 8;
        #pragma unroll
        for (int i = 0; i < 8; ++i) wreg[i] = *(const f16x8*)(src + i * 512);
    };
    auto wstore = [&]() {
        f16* dst = wmine + l * 8;
        #pragma unroll
        for (int i = 0; i < 8; ++i) *(f16x8*)(dst + i * 512) = wreg[i];
    };

    wload(g0); wstore();

    f32x4 acc[2][4] = {};
    for (int q = 0; q < cnt; ++q) {
        const int k = g0 + q;
        if (q + 1 < cnt) wload(k + 1);
        const int tap = k >> 1, hs = k & 1;
        const int du = tap / 9, rr = tap % 9, dv = rr / 3, dw = rr % 3;
        const int uu = u + du - 1;
        const bool uok = (unsigned)uu < 8u;
        const f16* xrow[2]; bool ok[2];
        #pragma unroll
        for (int aa = 0; aa < 2; ++aa) {
            int vs = (ah*2 + aa)*2 + lv + dv - 1, ws = lw + dw - 1;
            ok[aa] = uok && (unsigned)vs < 8u && (unsigned)ws < 8u;
            xrow[aa] = xbase + ((size_t)(uu*64 + vs*8 + ws) << 7) + khi*8;
        }
        const f16* wrow = wmine + (l & 15)*64;
        const int schi = ((khi    ) ^ lw) * 8;
        const int sclo = ((4 + khi) ^ lw) * 8;
        f16x8 ahi[2], alo[2], bhi[4], blo[4];
        #pragma unroll
        for (int aa = 0; aa < 2; ++aa) {
            f16x8 v = {0,0,0,0,0,0,0,0}, v2 = v;
            if (ok[aa]) {
                v  = *(const f16x8*)(xrow[aa] + hs*32);
                v2 = *(const f16x8*)(xrow[aa] + 64 + hs*32);
            }
            ahi[aa] = v; alo[aa] = v2;
        }
        #pragma unroll
        for (int n = 0; n < 4; ++n) {
            bhi[n] = *(const f16x8*)(wrow + n*1024 + schi);
            blo[n] = *(const f16x8*)(wrow + n*1024 + sclo);
        }
        #pragma unroll
        for (int aa = 0; aa < 2; ++aa)
            #pragma unroll
            for (int n = 0; n < 4; ++n)
                acc[aa][n] = __builtin_amdgcn_mfma_f32_16x16x32_f16(
                    ahi[aa], bhi[n], acc[aa][n], 0, 0, 0);
        #pragma unroll
        for (int aa = 0; aa < 2; ++aa)
            #pragma unroll
            for (int n = 0; n < 4; ++n)
                acc[aa][n] = __builtin_amdgcn_mfma_f32_16x16x32_f16(
                    alo[aa], bhi[n], acc[aa][n], 0, 0, 0);
        #pragma unroll
        for (int aa = 0; aa < 2; ++aa)
            #pragma unroll
            for (int n = 0; n < 4; ++n)
                acc[aa][n] = __builtin_amdgcn_mfma_f32_16x16x32_f16(
                    ahi[aa], blo[n], acc[aa][n], 0, 0, 0);
        if (q + 1 < cnt) wstore();
    }

    f32x4* red = (f32x4*)smem;
    {
        f32x4* mine = red + (size_t)(wid * 64 + l) * 8;
        #pragma unroll
        for (int aa = 0; aa < 2; ++aa)
            #pragma unroll
            for (int n = 0; n < 4; ++n)
                mine[(aa * 4 + n) ^ lw] = acc[aa][n];
    }
    __syncthreads();
    {
        float* yp = J.y + (size_t)kb * GPART;
        const int aa = (t >> 7) & 1, nsel = (t >> 6) & 1, ll = t & 63;
        #pragma unroll
        for (int ni = 0; ni < 2; ++ni) {
            const int n = nsel*2 + ni;
            const int ch = (aa * 4 + n) ^ (ll & 7);
            f32x4 sv = red[(0 * 64 + ll) * 8 + ch]
                     + red[(1 * 64 + ll) * 8 + ch]
                     + red[(2 * 64 + ll) * 8 + ch]
                     + red[(3 * 64 + ll) * 8 + ch];
            const int co = cog * 64 + n * 16 + (ll & 15);
            #pragma unroll
            for (int r = 0; r < 4; ++r) {
                int vox = (ah*2 + aa) * 16 + (ll >> 4) * 4 + r;
                yp[(size_t)(slab * 512 + u * 64 + vox) * 256 + co]
                    = sv[r] * 0.015625f;            // /64 (w' scale)
            }
        }
    }
    __syncthreads();    // LDS reuse guard for the next grid-strided tile
}

__device__ void gates_task(const GJob& J, int bx, int t) {
    const int wid = t >> 6, lane = t & 63;
    const int row = bx * 4 + wid;             // nc*512 + vox, < 1024
    const int nc = row >> 9, vox = row & 511;

    const float* gA = J.giA + (size_t)row*256;
    const float* gB = J.giB + (size_t)row*256;
    float a0 = gA[lane]     + gB[lane]     + J.bin[lane];
    float a1 = gA[64+lane]  + gB[64+lane]  + J.bin[64+lane];
    float a2 = gA[128+lane] + gB[128+lane] + J.bin[128+lane];
    float a3 = gA[192+lane] + gB[192+lane] + J.bin[192+lane];
    float mu1 = wred_sum(a0+a1+a2+a3) * (1.f/256.f);
    float d0=a0-mu1, d1=a1-mu1, d2=a2-mu1, d3=a3-mu1;
    float v1 = wred_sum(d0*d0+d1*d1+d2*d2+d3*d3) * (1.f/256.f);
    float rs1 = rsqrtf(v1 + 1e-5f);

    float b0, b1, b2, b3;
    if (J.k0) {
        b0 = J.bhb[lane]; b1 = J.bhb[64+lane];
        b2 = J.bhb[128+lane]; b3 = J.bhb[192+lane];
    } else {
        const float* hA = J.ghA + (size_t)row*256;
        const float* hB = J.ghB + (size_t)row*256;
        b0 = hA[lane]     + hB[lane]     + J.bhb[lane];
        b1 = hA[64+lane]  + hB[64+lane]  + J.bhb[64+lane];
        b2 = hA[128+lane] + hB[128+lane] + J.bhb[128+lane];
        b3 = hA[192+lane] + hB[192+lane] + J.bhb[192+lane];
    }
    float mu2 = wred_sum(b0+b1+b2+b3) * (1.f/256.f);
    float e0=b0-mu2, e1=b1-mu2, e2=b2-mu2, e3=b3-mu2;
    float v2 = wred_sum(e0*e0+e1*e1+e2*e2+e3*e3) * (1.f/256.f);
    float rs2 = rsqrtf(v2 + 1e-5f);

    float Ig = d0*rs1*J.ginw[lane]     + J.ginb[lane]     + e0*rs2*J.ghw[lane]     + J.ghb[lane];
    float Fg = d1*rs1*J.ginw[64+lane]  + J.ginb[64+lane]  + e1*rs2*J.ghw[64+lane]  + J.ghb[64+lane];
    float Cg = d2*rs1*J.ginw[128+lane] + J.ginb[128+lane] + e2*rs2*J.ghw[128+lane] + J.ghb[128+lane];
    float Og = d3*rs1*J.ginw[192+lane] + J.ginb[192+lane] + e3*rs2*J.ghw[192+lane] + J.ghb[192+lane];

    float c_old = J.k0 ? 0.f : J.cx[(size_t)row*64 + lane];
    float c_new = fsig(Fg)*c_old + fsig(Ig)*ftanh(Cg);
    float h_new = fsig(Og)*ftanh(c_new);
    J.cx[(size_t)row*64 + lane] = c_new;
    size_t hb = ((size_t)(nc*7 + J.k)*512 + vox)*128 + lane;
    f16 hi = (f16)h_new;
    J.h16[hb]      = hi;
    J.h16[hb + 64] = (f16)(h_new - (float)hi);
}

// ---- the cooperative mega kernel ----
__global__ __launch_bounds__(256, 3) void mega_kernel(MegaArgs A)
{
    cg::grid_group gg = cg::this_grid();
    __shared__ float4 smem[2048];          // 32 KiB
    const int nb = gridDim.x, bid = blockIdx.x, t = threadIdx.x;
    const f16* win0 = A.wp;
    const f16* wh0  = A.wp + WPT;
    const f16* win1 = A.wp + 2*WPT;
    const f16* wh1  = A.wp + 3*WPT;

    // phase 0: embed + weight pack (1900 tasks)
    for (int task = bid; task < 1900; task += nb) prep_task(A, task, t);
    gg.sync();

    // phase 1: all 7 recurrence-free layer-1 input convs (7 x 256 tiles)
    for (int task = bid; task < 1792; task += nb) {
        int s = task >> 8;
        MJob m = { A.h1 + (size_t)s*XSP, win0, A.gi1 + (size_t)s*2*GPART };
        conv_tile(m, task & 255, t, smem);
    }
    gg.sync();

    // phase 2: the recurrence
    for (int s = 0; s <= 7; ++s) {
        GJob gj0, gj1; int ngj = 0;
        if (s <= 6) {
            gj0 = { A.gi1 + (size_t)s*2*GPART, A.gi1 + (size_t)s*2*GPART + GPART,
                    A.ghat1, A.ghat1 + GPART, A.bin_, A.bh,
                    A.gin_w, A.gin_b, A.gh_w, A.gh_b, A.cx1, A.h1, s, s == 0 };
            ngj = 1;
        }
        if (s >= 1) {
            GJob g2 = { A.gi2, A.gi2 + GPART, A.ghat2, A.ghat2 + GPART,
                        A.bin_ + 256, A.bh + 256, A.gin_w + 256, A.gin_b + 256,
                        A.gh_w + 256, A.gh_b + 256, A.cx2, A.h2, s - 1, s == 1 };
            if (ngj == 0) gj0 = g2; else gj1 = g2;
            ++ngj;
        }
        for (int task = bid; task < ngj*256; task += nb)
            gates_task((task >> 8) ? gj1 : gj0, task & 255, t);
        gg.sync();

        MJob cj0{}, cj1{}, cj2{}; int ncj = 0;
        if (s <= 5) { cj0 = { A.h1 + (size_t)s*XSP, wh0, A.ghat1 }; ncj = 1; }
        if (s <= 6) {
            MJob m = { A.h1 + (size_t)s*XSP, win1, A.gi2 };
            if (ncj == 0) cj0 = m; else cj1 = m;
            ++ncj;
        }
        if (s >= 1 && s <= 6) {
            MJob m = { A.h2 + (size_t)(s-1)*XSP, wh1, A.ghat2 };
            if (ncj == 0) cj0 = m; else if (ncj == 1) cj1 = m; else cj2 = m;
            ++ncj;
        }
        if (ncj) {
            for (int task = bid; task < ncj*256; task += nb) {
                int q = task >> 8;
                conv_tile(q == 0 ? cj0 : (q == 1 ? cj1 : cj2), task & 255, t, smem);
            }
            gg.sync();
        }
    }
}

// Head: unchanged from r18 (192 blocks x 16 vox, one loss atomic per block).
__global__ __launch_bounds__(256) void head_kernel(
    const f16* __restrict__ h,        // [2][7][512][128] hi/lo
    const float* __restrict__ w1, const float* __restrict__ b1,
    const float* __restrict__ lng, const float* __restrict__ lnb,
    const float* __restrict__ w2, const float* __restrict__ b2,
    const int* __restrict__ ncode,
    float* __restrict__ out)
{
    __shared__ float hsm[16][64];
    __shared__ float zv[16][64];
    __shared__ float lg[10240];               // [512 co][16 vox] stride 20
    __shared__ float lsum[16];
    const int blk = blockIdx.x;               // 192 = n(2) x sn(3) x vg(32)
    const int n = blk / 96;
    const int sn = (blk / 32) % 3;
    const int vox0 = (blk & 31) * 16;
    const int t = threadIdx.x, wid = t >> 6, lane = t & 63;

    for (int idx = t; idx < 1024; idx += 256) {
        int vr = idx >> 6, ch = idx & 63;
        const f16* hv = h + (size_t)((n*7 + sn + 4)*512 + vox0 + vr)*128;
        hsm[vr][ch] = (float)hv[ch] + (float)hv[64 + ch];
    }
    __syncthreads();

    float yva[4], yvb[4];
    #pragma unroll
    for (int r = 0; r < 4; ++r) { yva[r] = b1[lane]; yvb[r] = 0.f; }
    for (int kk = 0; kk < 64; kk += 2) {
        float w1a = w1[kk*64 + lane], w1b = w1[(kk+1)*64 + lane];
        #pragma unroll
        for (int r = 0; r < 4; ++r) {
            yva[r] = fmaf(hsm[wid*4 + r][kk],     w1a, yva[r]);
            yvb[r] = fmaf(hsm[wid*4 + r][kk + 1], w1b, yvb[r]);
        }
    }
    #pragma unroll
    for (int r = 0; r < 4; ++r) {
        float yv = yva[r] + yvb[r];
        float mu = wred_sum(yv) * (1.f/64.f);
        float d = yv - mu;
        float var = wred_sum(d*d) * (1.f/64.f);
        float ln = d * rsqrtf(var + 1e-5f) * lng[lane] + lnb[lane];
        zv[wid*4 + r][lane] = 0.5f * ln * (1.f + erff(ln * 0.70710678118654752f));
    }
    __syncthreads();

    float l[4][8];
    #pragma unroll
    for (int r = 0; r < 4; ++r)
        #pragma unroll
        for (int j = 0; j < 8; ++j) l[r][j] = b2[j*64 + lane];
    for (int kk = 0; kk < 64; ++kk) {
        float wv[8];
        #pragma unroll
        for (int j = 0; j < 8; ++j) wv[j] = w2[kk*512 + j*64 + lane];
        #pragma unroll
        for (int r = 0; r < 4; ++r) {
            float zz = zv[wid*4 + r][kk];
            #pragma unroll
            for (int j = 0; j < 8; ++j) l[r][j] = fmaf(zz, wv[j], l[r][j]);
        }
    }
    #pragma unroll
    for (int r = 0; r < 4; ++r)
        #pragma unroll
        for (int j = 0; j < 8; ++j)
            lg[(j*64 + lane)*20 + wid*4 + r] = l[r][j];

    #pragma unroll
    for (int r = 0; r < 4; ++r) {
        float m = l[r][0]; int mi = lane;
        #pragma unroll
        for (int j = 1; j < 8; ++j)
            if (l[r][j] > m) { m = l[r][j]; mi = j*64 + lane; }
        #pragma unroll
        for (int o = 32; o > 0; o >>= 1) {
            float om = __shfl_down(m, o, 64);
            int   oi = __shfl_down(mi, o, 64);
            if (om > m || (om == m && oi < mi)) { m = om; mi = oi; }
        }
        float maxv = __shfl(m, 0, 64);
        int   maxi = __shfl(mi, 0, 64);
        float es = 0.f;
        #pragma unroll
        for (int j = 0; j < 8; ++j) es += __expf(l[r][j] - maxv);
        float sum = wred_sum(es);
        if (lane == 0) {
            int vox = vox0 + wid*4 + r;
            int target = ncode[(n*3 + sn)*512 + vox];
            float logp = lg[target*20 + wid*4 + r] - maxv - __logf(sum);
            lsum[wid*4 + r] = -logp * (1.f/3072.f);
            out[1572865 + (n*3 + sn)*512 + vox] = (float)maxi;
        }
    }

    __syncthreads();
    if (t == 0) {
        float s = 0.f;
        #pragma unroll
        for (int i = 0; i < 16; ++i) s += lsum[i];
        atomicAdd(out + 1572864, s);
    }
    for (int e = t; e < 2048; e += 256) {
        int co = e >> 2, p = e & 3;
        int base = co*20 + p*4;
        float4 o4 = { lg[base], lg[base+1], lg[base+2], lg[base+3] };
        *(float4*)(out + (size_t)((n*512 + co)*3 + sn)*512 + vox0 + p*4) = o4;
    }
}

extern "C" void kernel_launch(void* const* d_in, const int* in_sizes, int n_in,
                              void* d_out, int out_size, void* d_ws, size_t ws_size,
                              hipStream_t stream) {
    (void)in_sizes; (void)n_in; (void)out_size; (void)ws_size;
    const int*   code  = (const int*)d_in[0];
    const int*   ncode = (const int*)d_in[1];
    const float* emb   = (const float*)d_in[2];
    const float* win   = (const float*)d_in[3];
    const float* bin_  = (const float*)d_in[4];
    const float* gin_w = (const float*)d_in[5];
    const float* gin_b = (const float*)d_in[6];
    const float* wh    = (const float*)d_in[7];
    const float* bh    = (const float*)d_in[8];
    const float* gh_w  = (const float*)d_in[9];
    const float* gh_b  = (const float*)d_in[10];
    const float* w1    = (const float*)d_in[11];
    const float* b1    = (const float*)d_in[12];
    const float* ln_g  = (const float*)d_in[13];
    const float* ln_b  = (const float*)d_in[14];
    const float* w2    = (const float*)d_in[15];
    const float* b2    = (const float*)d_in[16];
    float* out = (float*)d_out;

    float* base  = (float*)d_ws;
    f16*   wp    = (f16*)base;                    // 1,769,472 floats
    f16*   h1    = (f16*)(base + 1769472);        // 458,752 floats
    f16*   h2    = (f16*)(base + 2228224);        // 458,752 floats
    float* gi1   = base + 2686976;                // 7 slots x 2 partials
    float* gi2   = gi1 + 7*2*GPART;
    float* ghat1 = gi2 + 2*GPART;
    float* ghat2 = ghat1 + 2*GPART;
    float* cx1   = ghat2 + 2*GPART;
    float* cx2   = cx1 + 65536;                   // end ~8.06M floats (~32MB)

    MegaArgs A = { code, ncode, emb, win, wh, bin_, bh,
                   gin_w, gin_b, gh_w, gh_b,
                   wp, h1, h2, gi1, gi2, ghat1, ghat2, cx1, cx2 };

    hipMemsetAsync(out + 1572864, 0, sizeof(float), stream);   // loss accumulator

    static int nblk = 0;
    if (nblk == 0) {
        int occ = 0;
        if (hipOccupancyMaxActiveBlocksPerMultiprocessor(&occ, mega_kernel, 256, 0)
                != hipSuccess || occ < 1)
            occ = 1;
        nblk = occ * 256;                 // 256 CUs on MI355X
        if (nblk > 768) nblk = 768;       // 3 x 256-tile task waves max useful
    }
    void* kargs[] = { (void*)&A };
    hipLaunchCooperativeKernel(mega_kernel, dim3(nblk), dim3(256), kargs, 0, stream);

    head_kernel<<<192, 256, 0, stream>>>(h2, w1, b1, ln_g, ln_b, w2, b2, ncode, out);
}

// Round 6
// 486.070 us; speedup vs baseline: 1.7867x; 1.7867x over previous
//
#include <hip/hip_runtime.h>

// r20: revert cooperative launch (cg grid.sync measured ~30us/sync -> 868us).
// Keep r18's launch skeleton + math (known 305us, absmax 0.0039) but halve the
// serial launch count with a LIGHTWEIGHT one-shot flag barrier (device atomicAdd
// + s_sleep spin, one fresh counter per barrier instance, zeroed by a 64B
// memset in-graph):
//   prep_conv: embed+wsplit -> bar -> all 1792 layer-1 input conv tiles
//   step s=0..6: gates (<=512 tasks) -> bar -> convs rec1/in2/rec2 (<=768)
//   head: gates2(6) phase -> bar -> head (first 192 of 256 blocks)
// Grid occupancy-clamped (<=3 blocks/CU guaranteed resident) so the spin
// barrier cannot deadlock. 20 -> 11 dispatches.

typedef _Float16 f16;
typedef _Float16 f16x8 __attribute__((ext_vector_type(8)));
typedef float    f32x4 __attribute__((ext_vector_type(4)));

#define WSTRIDE 442368   // fp32 weight elements per layer: 27*64*256
#define WPT     884736   // halfs per packed tensor: 54*256*64
#define XSP     65536    // halfs per s-slab of h: 512*128
#define HSP     458752   // halfs per nc of h: 7*512*128
#define GPART   262144   // floats per conv partial buffer: 2*512*256

__device__ __forceinline__ float wred_sum(float v) {
    #pragma unroll
    for (int o = 32; o > 0; o >>= 1) v += __shfl_down(v, o, 64);
    return __shfl(v, 0, 64);
}
__device__ __forceinline__ float fsig(float x)  { return 1.f / (1.f + __expf(-x)); }
__device__ __forceinline__ float ftanh(float x) { return 1.f - 2.f / (__expf(2.f*x) + 1.f); }

// One-shot grid barrier: counter starts 0 (memset in-graph), each block
// arrives once. Device-scope RMW (m20: atomicAdd on global is device-scope);
// s_sleep(8) backoff keeps coherence-point contention low.
__device__ __forceinline__ void flagbar(int* ctr, int nb) {
    __syncthreads();
    if (threadIdx.x == 0) {
        __threadfence();                       // release block's stores
        atomicAdd(ctr, 1);
        while (atomicAdd(ctr, 0) < nb) __builtin_amdgcn_s_sleep(8);
        __threadfence();                       // acquire (inv L1/L2)
    }
    __syncthreads();
}

struct GJob {
    const float* giA; const float* giB;
    const float* ghA; const float* ghB;
    const float* bin; const float* bhb;
    const float* ginw; const float* ginb;
    const float* ghw;  const float* ghb;
    float* cx; f16* h16; int k; int k0;
};
struct MegaArgs {
    const int* code; const int* ncode; const float* emb;
    const float* win; const float* wh;
    const float* bin_; const float* bh;
    const float* gin_w; const float* gin_b;
    const float* gh_w;  const float* gh_b;
    f16* wp; f16* h1; f16* h2;
    float* gi1; float* gi2; float* ghat1; float* ghat2;
    float* cx1; float* cx2;
};

// ---- phase bodies (verbatim r18/r19 logic, known-good) ----

__device__ void prep_task(const MegaArgs& A, int task, int t) {
    if (task < 1792) {
        int e = task * 256 + t;          // < 458752
        int ch = e & 63;
        int pos = e >> 6;                // nc*7*512 + s*512 + vox
        int vox = pos & 511;
        int tt = pos >> 9;
        int s = tt % 7, nc = tt / 7;
        int tok = (s < 5) ? A.code[(nc*5 + s)*512 + vox]
                          : A.ncode[(nc*3 + (s-5))*512 + vox];
        float x = A.emb[tok*64 + ch];
        f16 hi = (f16)x;
        A.h1[(size_t)pos*128 + ch]      = hi;
        A.h1[(size_t)pos*128 + 64 + ch] = (f16)(x - (float)hi);
    } else {
        int b = task - 1792;             // 108 = 4 tensors * 27 taps
        int tensor = b / 27, tap = b % 27;
        const float* src = ((tensor & 1) ? A.wh : A.win)
                         + (tensor >> 1) * WSTRIDE + tap * 16384;
        int co = t;
        int sw = co & 7;
        #pragma unroll
        for (int hs = 0; hs < 2; ++hs) {
            f16* dst = A.wp + (((size_t)tensor*27 + tap)*2 + hs)*16384 + co*64;
            #pragma unroll
            for (int j = 0; j < 4; ++j) {
                f16x8 hi8, lo8;
                #pragma unroll
                for (int m = 0; m < 8; ++m) {
                    float w = src[(hs*32 + j*8 + m)*256 + co] * 64.f;
                    f16 hv = (f16)w;
                    hi8[m] = hv;
                    lo8[m] = (f16)(w - (float)hv);
                }
                *(f16x8*)(dst + ((j     ^ sw))*8) = hi8;
                *(f16x8*)(dst + (((4+j) ^ sw))*8) = lo8;
            }
        }
    }
}

// One conv tile: 32-vox a-half x 64 co, K-atoms split over 8 groups
// (kb*4+wid). 3-segment hi/lo f16 MFMA, partial written to y + kb*GPART.
__device__ void conv_tile(const f16* X, const f16* W, float* Y,
                          int bx, int t, float4* smem) {
    f16* wbuf = (f16*)smem;
    const int cog = bx & 3, u = (bx >> 2) & 7, slab = (bx >> 5) & 1;
    const int ah = (bx >> 6) & 1, kb = bx >> 7;
    const int wid = t >> 6, l = t & 63;
    const int lv = (l >> 3) & 1, lw = l & 7, khi = l >> 4;

    const int gid = kb*4 + wid;
    const int g0  = (gid < 6) ? gid*7 : 42 + (gid - 6)*6;
    const int cnt = (gid < 6) ? 7 : 6;

    const f16* xbase = X + (size_t)slab * HSP;
    const f16* wjob  = W + (size_t)cog * 4096;        // + atom*16384
    f16* wmine = wbuf + wid * 4096;                   // 8KB, single-buffered

    f16x8 wreg[8];
    auto wload = [&](int k) {
        const f16* src = wjob + (size_t)k * 16384 + l * 8;
        #pragma unroll
        for (int i = 0; i < 8; ++i) wreg[i] = *(const f16x8*)(src + i * 512);
    };
    auto wstore = [&]() {
        f16* dst = wmine + l * 8;
        #pragma unroll
        for (int i = 0; i < 8; ++i) *(f16x8*)(dst + i * 512) = wreg[i];
    };

    wload(g0); wstore();

    f32x4 acc[2][4] = {};
    for (int q = 0; q < cnt; ++q) {
        const int k = g0 + q;
        if (q + 1 < cnt) wload(k + 1);
        const int tap = k >> 1, hs = k & 1;
        const int du = tap / 9, rr = tap % 9, dv = rr / 3, dw = rr % 3;
        const int uu = u + du - 1;
        const bool uok = (unsigned)uu < 8u;
        const f16* xrow[2]; bool ok[2];
        #pragma unroll
        for (int aa = 0; aa < 2; ++aa) {
            int vs = (ah*2 + aa)*2 + lv + dv - 1, ws = lw + dw - 1;
            ok[aa] = uok && (unsigned)vs < 8u && (unsigned)ws < 8u;
            xrow[aa] = xbase + ((size_t)(uu*64 + vs*8 + ws) << 7) + khi*8;
        }
        const f16* wrow = wmine + (l & 15)*64;
        const int schi = ((khi    ) ^ lw) * 8;
        const int sclo = ((4 + khi) ^ lw) * 8;
        f16x8 ahi[2], alo[2], bhi[4], blo[4];
        #pragma unroll
        for (int aa = 0; aa < 2; ++aa) {
            f16x8 v = {0,0,0,0,0,0,0,0}, v2 = v;
            if (ok[aa]) {
                v  = *(const f16x8*)(xrow[aa] + hs*32);
                v2 = *(const f16x8*)(xrow[aa] + 64 + hs*32);
            }
            ahi[aa] = v; alo[aa] = v2;
        }
        #pragma unroll
        for (int n = 0; n < 4; ++n) {
            bhi[n] = *(const f16x8*)(wrow + n*1024 + schi);
            blo[n] = *(const f16x8*)(wrow + n*1024 + sclo);
        }
        #pragma unroll
        for (int aa = 0; aa < 2; ++aa)
            #pragma unroll
            for (int n = 0; n < 4; ++n)
                acc[aa][n] = __builtin_amdgcn_mfma_f32_16x16x32_f16(
                    ahi[aa], bhi[n], acc[aa][n], 0, 0, 0);
        #pragma unroll
        for (int aa = 0; aa < 2; ++aa)
            #pragma unroll
            for (int n = 0; n < 4; ++n)
                acc[aa][n] = __builtin_amdgcn_mfma_f32_16x16x32_f16(
                    alo[aa], bhi[n], acc[aa][n], 0, 0, 0);
        #pragma unroll
        for (int aa = 0; aa < 2; ++aa)
            #pragma unroll
            for (int n = 0; n < 4; ++n)
                acc[aa][n] = __builtin_amdgcn_mfma_f32_16x16x32_f16(
                    ahi[aa], blo[n], acc[aa][n], 0, 0, 0);
        if (q + 1 < cnt) wstore();
    }

    f32x4* red = (f32x4*)smem;
    {
        f32x4* mine = red + (size_t)(wid * 64 + l) * 8;
        #pragma unroll
        for (int aa = 0; aa < 2; ++aa)
            #pragma unroll
            for (int n = 0; n < 4; ++n)
                mine[(aa * 4 + n) ^ lw] = acc[aa][n];
    }
    __syncthreads();
    {
        float* yp = Y + (size_t)kb * GPART;
        const int aa = (t >> 7) & 1, nsel = (t >> 6) & 1, ll = t & 63;
        #pragma unroll
        for (int ni = 0; ni < 2; ++ni) {
            const int n = nsel*2 + ni;
            const int ch = (aa * 4 + n) ^ (ll & 7);
            f32x4 sv = red[(0 * 64 + ll) * 8 + ch]
                     + red[(1 * 64 + ll) * 8 + ch]
                     + red[(2 * 64 + ll) * 8 + ch]
                     + red[(3 * 64 + ll) * 8 + ch];
            const int co = cog * 64 + n * 16 + (ll & 15);
            #pragma unroll
            for (int r = 0; r < 4; ++r) {
                int vox = (ah*2 + aa) * 16 + (ll >> 4) * 4 + r;
                yp[(size_t)(slab * 512 + u * 64 + vox) * 256 + co]
                    = sv[r] * 0.015625f;            // /64 (w' scale)
            }
        }
    }
    __syncthreads();    // LDS reuse guard for the next grid-strided tile
}

__device__ void gates_task(const GJob& J, int bx, int t) {
    const int wid = t >> 6, lane = t & 63;
    const int row = bx * 4 + wid;             // nc*512 + vox, < 1024
    const int nc = row >> 9, vox = row & 511;

    const float* gA = J.giA + (size_t)row*256;
    const float* gB = J.giB + (size_t)row*256;
    float a0 = gA[lane]     + gB[lane]     + J.bin[lane];
    float a1 = gA[64+lane]  + gB[64+lane]  + J.bin[64+lane];
    float a2 = gA[128+lane] + gB[128+lane] + J.bin[128+lane];
    float a3 = gA[192+lane] + gB[192+lane] + J.bin[192+lane];
    float mu1 = wred_sum(a0+a1+a2+a3) * (1.f/256.f);
    float d0=a0-mu1, d1=a1-mu1, d2=a2-mu1, d3=a3-mu1;
    float v1 = wred_sum(d0*d0+d1*d1+d2*d2+d3*d3) * (1.f/256.f);
    float rs1 = rsqrtf(v1 + 1e-5f);

    float b0, b1, b2, b3;
    if (J.k0) {
        b0 = J.bhb[lane]; b1 = J.bhb[64+lane];
        b2 = J.bhb[128+lane]; b3 = J.bhb[192+lane];
    } else {
        const float* hA = J.ghA + (size_t)row*256;
        const float* hB = J.ghB + (size_t)row*256;
        b0 = hA[lane]     + hB[lane]     + J.bhb[lane];
        b1 = hA[64+lane]  + hB[64+lane]  + J.bhb[64+lane];
        b2 = hA[128+lane] + hB[128+lane] + J.bhb[128+lane];
        b3 = hA[192+lane] + hB[192+lane] + J.bhb[192+lane];
    }
    float mu2 = wred_sum(b0+b1+b2+b3) * (1.f/256.f);
    float e0=b0-mu2, e1=b1-mu2, e2=b2-mu2, e3=b3-mu2;
    float v2 = wred_sum(e0*e0+e1*e1+e2*e2+e3*e3) * (1.f/256.f);
    float rs2 = rsqrtf(v2 + 1e-5f);

    float Ig = d0*rs1*J.ginw[lane]     + J.ginb[lane]     + e0*rs2*J.ghw[lane]     + J.ghb[lane];
    float Fg = d1*rs1*J.ginw[64+lane]  + J.ginb[64+lane]  + e1*rs2*J.ghw[64+lane]  + J.ghb[64+lane];
    float Cg = d2*rs1*J.ginw[128+lane] + J.ginb[128+lane] + e2*rs2*J.ghw[128+lane] + J.ghb[128+lane];
    float Og = d3*rs1*J.ginw[192+lane] + J.ginb[192+lane] + e3*rs2*J.ghw[192+lane] + J.ghb[192+lane];

    float c_old = J.k0 ? 0.f : J.cx[(size_t)row*64 + lane];
    float c_new = fsig(Fg)*c_old + fsig(Ig)*ftanh(Cg);
    float h_new = fsig(Og)*ftanh(c_new);
    J.cx[(size_t)row*64 + lane] = c_new;
    size_t hb = ((size_t)(nc*7 + J.k)*512 + vox)*128 + lane;
    f16 hi = (f16)h_new;
    J.h16[hb]      = hi;
    J.h16[hb + 64] = (f16)(h_new - (float)hi);
}

// ---- kernels ----

// prep (embed + wpack) -> bar -> all 7 layer-1 input convs (1792 tiles)
__global__ __launch_bounds__(256, 3) void prep_conv_kernel(MegaArgs A, int* bar, int nb)
{
    __shared__ float4 smem[2048];          // 32 KiB
    const int bid = blockIdx.x, t = threadIdx.x;
    for (int task = bid; task < 1900; task += nb) prep_task(A, task, t);
    flagbar(bar, nb);
    for (int task = bid; task < 1792; task += nb) {
        int s = task >> 8;
        conv_tile(A.h1 + (size_t)s*XSP, A.wp,
                  A.gi1 + (size_t)s*2*GPART, task & 255, t, smem);
    }
}

// one recurrence step: gates1(s) [s<=6] + gates2(s-1) [s>=1] -> bar ->
// convs rec1(s)/in2(s)/rec2(s-1)
__global__ __launch_bounds__(256, 3) void step_kernel(MegaArgs A, int s, int* bar, int nb)
{
    __shared__ float4 smem[2048];
    const int bid = blockIdx.x, t = threadIdx.x;

    GJob gj0, gj1; int ngj = 0;
    {
        GJob g1 = { A.gi1 + (size_t)s*2*GPART, A.gi1 + (size_t)s*2*GPART + GPART,
                    A.ghat1, A.ghat1 + GPART, A.bin_, A.bh,
                    A.gin_w, A.gin_b, A.gh_w, A.gh_b, A.cx1, A.h1, s, s == 0 };
        gj0 = g1; ngj = 1;            // s<=6 always true in this loop
    }
    if (s >= 1) {
        GJob g2 = { A.gi2, A.gi2 + GPART, A.ghat2, A.ghat2 + GPART,
                    A.bin_ + 256, A.bh + 256, A.gin_w + 256, A.gin_b + 256,
                    A.gh_w + 256, A.gh_b + 256, A.cx2, A.h2, s - 1, s == 1 };
        gj1 = g2; ngj = 2;
    }
    for (int task = bid; task < ngj*256; task += nb) {
        if ((task >> 8) == 0) gates_task(gj0, task & 255, t);
        else                  gates_task(gj1, task & 255, t);
    }

    // conv job pointer sets (scalar selects, no runtime-indexed arrays)
    const f16 *x0=nullptr,*w0=nullptr; float* y0=nullptr;
    const f16 *x1=nullptr,*w1=nullptr; float* y1=nullptr;
    const f16 *x2=nullptr,*w2=nullptr; float* y2=nullptr;
    int ncj = 0;
    if (s <= 5) { x0 = A.h1 + (size_t)s*XSP; w0 = A.wp + WPT; y0 = A.ghat1; ncj = 1; }
    {   // in2(s), s<=6 always
        const f16* x = A.h1 + (size_t)s*XSP; const f16* w = A.wp + 2*WPT; float* y = A.gi2;
        if (ncj == 0) { x0=x; w0=w; y0=y; } else { x1=x; w1=w; y1=y; }
        ++ncj;
    }
    if (s >= 1) {
        const f16* x = A.h2 + (size_t)(s-1)*XSP; const f16* w = A.wp + 3*WPT; float* y = A.ghat2;
        if (ncj == 1) { x1=x; w1=w; y1=y; } else { x2=x; w2=w; y2=y; }
        ++ncj;
    }

    flagbar(bar, nb);

    for (int task = bid; task < ncj*256; task += nb) {
        int q = task >> 8;
        const f16* xj = (q==0) ? x0 : (q==1) ? x1 : x2;
        const f16* wj = (q==0) ? w0 : (q==1) ? w1 : w2;
        float*     yj = (q==0) ? y0 : (q==1) ? y1 : y2;
        conv_tile(xj, wj, yj, task & 255, t, smem);
    }
}

// head: phase A = gates2(6) (256 blocks x 4 rows) -> bar -> phase B = head
// proper on the first 192 blocks (r18 body, one loss atomic per block).
__global__ __launch_bounds__(256) void head_kernel(MegaArgs A,
    const float* __restrict__ w1, const float* __restrict__ b1,
    const float* __restrict__ lng, const float* __restrict__ lnb,
    const float* __restrict__ w2, const float* __restrict__ b2,
    float* __restrict__ out, int* bar, int nb)
{
    {
        GJob gj = { A.gi2, A.gi2 + GPART, A.ghat2, A.ghat2 + GPART,
                    A.bin_ + 256, A.bh + 256, A.gin_w + 256, A.gin_b + 256,
                    A.gh_w + 256, A.gh_b + 256, A.cx2, A.h2, 6, 0 };
        gates_task(gj, blockIdx.x, threadIdx.x);
    }
    flagbar(bar, nb);
    if (blockIdx.x >= 192) return;

    const f16* h = A.h2;
    const int* ncode = A.ncode;
    __shared__ float hsm[16][64];
    __shared__ float zv[16][64];
    __shared__ float lg[10240];               // [512 co][16 vox] stride 20
    __shared__ float lsum[16];
    const int blk = blockIdx.x;               // 192 = n(2) x sn(3) x vg(32)
    const int n = blk / 96;
    const int sn = (blk / 32) % 3;
    const int vox0 = (blk & 31) * 16;
    const int t = threadIdx.x, wid = t >> 6, lane = t & 63;

    for (int idx = t; idx < 1024; idx += 256) {
        int vr = idx >> 6, ch = idx & 63;
        const f16* hv = h + (size_t)((n*7 + sn + 4)*512 + vox0 + vr)*128;
        hsm[vr][ch] = (float)hv[ch] + (float)hv[64 + ch];
    }
    __syncthreads();

    float yva[4], yvb[4];
    #pragma unroll
    for (int r = 0; r < 4; ++r) { yva[r] = b1[lane]; yvb[r] = 0.f; }
    for (int kk = 0; kk < 64; kk += 2) {
        float w1a = w1[kk*64 + lane], w1b = w1[(kk+1)*64 + lane];
        #pragma unroll
        for (int r = 0; r < 4; ++r) {
            yva[r] = fmaf(hsm[wid*4 + r][kk],     w1a, yva[r]);
            yvb[r] = fmaf(hsm[wid*4 + r][kk + 1], w1b, yvb[r]);
        }
    }
    #pragma unroll
    for (int r = 0; r < 4; ++r) {
        float yv = yva[r] + yvb[r];
        float mu = wred_sum(yv) * (1.f/64.f);
        float d = yv - mu;
        float var = wred_sum(d*d) * (1.f/64.f);
        float ln = d * rsqrtf(var + 1e-5f) * lng[lane] + lnb[lane];
        zv[wid*4 + r][lane] = 0.5f * ln * (1.f + erff(ln * 0.70710678118654752f));
    }
    __syncthreads();

    float l[4][8];
    #pragma unroll
    for (int r = 0; r < 4; ++r)
        #pragma unroll
        for (int j = 0; j < 8; ++j) l[r][j] = b2[j*64 + lane];
    for (int kk = 0; kk < 64; ++kk) {
        float wv[8];
        #pragma unroll
        for (int j = 0; j < 8; ++j) wv[j] = w2[kk*512 + j*64 + lane];
        #pragma unroll
        for (int r = 0; r < 4; ++r) {
            float zz = zv[wid*4 + r][kk];
            #pragma unroll
            for (int j = 0; j < 8; ++j) l[r][j] = fmaf(zz, wv[j], l[r][j]);
        }
    }
    #pragma unroll
    for (int r = 0; r < 4; ++r)
        #pragma unroll
        for (int j = 0; j < 8; ++j)
            lg[(j*64 + lane)*20 + wid*4 + r] = l[r][j];

    #pragma unroll
    for (int r = 0; r < 4; ++r) {
        float m = l[r][0]; int mi = lane;
        #pragma unroll
        for (int j = 1; j < 8; ++j)
            if (l[r][j] > m) { m = l[r][j]; mi = j*64 + lane; }
        #pragma unroll
        for (int o = 32; o > 0; o >>= 1) {
            float om = __shfl_down(m, o, 64);
            int   oi = __shfl_down(mi, o, 64);
            if (om > m || (om == m && oi < mi)) { m = om; mi = oi; }
        }
        float maxv = __shfl(m, 0, 64);
        int   maxi = __shfl(mi, 0, 64);
        float es = 0.f;
        #pragma unroll
        for (int j = 0; j < 8; ++j) es += __expf(l[r][j] - maxv);
        float sum = wred_sum(es);
        if (lane == 0) {
            int vox = vox0 + wid*4 + r;
            int target = ncode[(n*3 + sn)*512 + vox];
            float logp = lg[target*20 + wid*4 + r] - maxv - __logf(sum);
            lsum[wid*4 + r] = -logp * (1.f/3072.f);
            out[1572865 + (n*3 + sn)*512 + vox] = (float)maxi;
        }
    }

    __syncthreads();
    if (t == 0) {
        float s = 0.f;
        #pragma unroll
        for (int i = 0; i < 16; ++i) s += lsum[i];
        atomicAdd(out + 1572864, s);
    }
    for (int e = t; e < 2048; e += 256) {
        int co = e >> 2, p = e & 3;
        int base = co*20 + p*4;
        float4 o4 = { lg[base], lg[base+1], lg[base+2], lg[base+3] };
        *(float4*)(out + (size_t)((n*512 + co)*3 + sn)*512 + vox0 + p*4) = o4;
    }
}

extern "C" void kernel_launch(void* const* d_in, const int* in_sizes, int n_in,
                              void* d_out, int out_size, void* d_ws, size_t ws_size,
                              hipStream_t stream) {
    (void)in_sizes; (void)n_in; (void)out_size; (void)ws_size;
    const int*   code  = (const int*)d_in[0];
    const int*   ncode = (const int*)d_in[1];
    const float* emb   = (const float*)d_in[2];
    const float* win   = (const float*)d_in[3];
    const float* bin_  = (const float*)d_in[4];
    const float* gin_w = (const float*)d_in[5];
    const float* gin_b = (const float*)d_in[6];
    const float* wh    = (const float*)d_in[7];
    const float* bh    = (const float*)d_in[8];
    const float* gh_w  = (const float*)d_in[9];
    const float* gh_b  = (const float*)d_in[10];
    const float* w1    = (const float*)d_in[11];
    const float* b1    = (const float*)d_in[12];
    const float* ln_g  = (const float*)d_in[13];
    const float* ln_b  = (const float*)d_in[14];
    const float* w2    = (const float*)d_in[15];
    const float* b2    = (const float*)d_in[16];
    float* out = (float*)d_out;

    float* base  = (float*)d_ws;
    f16*   wp    = (f16*)base;                    // 1,769,472 floats
    f16*   h1    = (f16*)(base + 1769472);        // 458,752 floats
    f16*   h2    = (f16*)(base + 2228224);        // 458,752 floats
    float* gi1   = base + 2686976;                // 7 slots x 2 partials
    float* gi2   = gi1 + 7*2*GPART;               // base + 6356992
    float* ghat1 = gi2 + 2*GPART;                 // base + 6881280
    float* ghat2 = ghat1 + 2*GPART;               // base + 7405568
    float* cx1   = ghat2 + 2*GPART;               // base + 7929856
    float* cx2   = cx1 + 65536;                   // base + 7995392
    int*   bar   = (int*)(base + 8060928);        // 16 counters

    MegaArgs A = { code, ncode, emb, win, wh, bin_, bh,
                   gin_w, gin_b, gh_w, gh_b,
                   wp, h1, h2, gi1, gi2, ghat1, ghat2, cx1, cx2 };

    static int nb_prep = 0, nb_step = 0;
    if (nb_prep == 0) {
        int occ = 0;
        if (hipOccupancyMaxActiveBlocksPerMultiprocessor(&occ, prep_conv_kernel,
                256, 0) != hipSuccess || occ < 1) occ = 1;
        if (occ > 3) occ = 3;                 // guaranteed-resident clamp
        nb_prep = occ * 256;
        occ = 0;
        if (hipOccupancyMaxActiveBlocksPerMultiprocessor(&occ, step_kernel,
                256, 0) != hipSuccess || occ < 1) occ = 1;
        if (occ > 3) occ = 3;
        nb_step = occ * 256;
    }

    hipMemsetAsync(out + 1572864, 0, sizeof(float), stream);   // loss accumulator
    hipMemsetAsync(bar, 0, 16 * sizeof(int), stream);          // barrier counters

    prep_conv_kernel<<<nb_prep, 256, 0, stream>>>(A, bar + 0, nb_prep);
    for (int s = 0; s <= 6; ++s)
        step_kernel<<<nb_step, 256, 0, stream>>>(A, s, bar + 1 + s, nb_step);
    head_kernel<<<256, 256, 0, stream>>>(A, w1, b1, ln_g, ln_b, w2, b2,
                                         out, bar + 8, 256);
}

// Round 8
// 485.953 us; speedup vs baseline: 1.7871x; 1.0002x over previous
//
#include <hip/hip_runtime.h>

// r22: r21 with the compile fix — __hip_atomic_fence doesn't exist on this
// ROCm; use __threadfence() (device-scope, same semantics r20 used). The
// actual experiment is unchanged: barrier POLL is an agent-scope atomic LOAD
// (concurrent LLC service) instead of r20's atomicAdd(ctr,0) RMW (exclusive-
// ownership serialized -> ~120us idle spin at 768 blocks).
// Structure: memset x2 + prep_conv + 7 steps + head = 11 dispatches.
// Math verbatim r18 (absmax 0.00390625).

typedef _Float16 f16;
typedef _Float16 f16x8 __attribute__((ext_vector_type(8)));
typedef float    f32x4 __attribute__((ext_vector_type(4)));

#define WSTRIDE 442368   // fp32 weight elements per layer: 27*64*256
#define WPT     884736   // halfs per packed tensor: 54*256*64
#define XSP     65536    // halfs per s-slab of h: 512*128
#define HSP     458752   // halfs per nc of h: 7*512*128
#define GPART   262144   // floats per conv partial buffer: 2*512*256

__device__ __forceinline__ float wred_sum(float v) {
    #pragma unroll
    for (int o = 32; o > 0; o >>= 1) v += __shfl_down(v, o, 64);
    return __shfl(v, 0, 64);
}
__device__ __forceinline__ float fsig(float x)  { return 1.f / (1.f + __expf(-x)); }
__device__ __forceinline__ float ftanh(float x) { return 1.f - 2.f / (__expf(2.f*x) + 1.f); }

// One-shot grid barrier. Poll = atomic LOAD (agent scope, relaxed): no
// exclusive ownership, concurrent service from LLC. Arrival = fetch_add.
// __threadfence() = device-scope release/acquire around the protocol.
__device__ __forceinline__ void flagbar(int* ctr, int nb) {
    __syncthreads();
    if (threadIdx.x == 0) {
        __threadfence();                       // release block's stores
        __hip_atomic_fetch_add(ctr, 1, __ATOMIC_RELAXED, __HIP_MEMORY_SCOPE_AGENT);
        while (__hip_atomic_load(ctr, __ATOMIC_RELAXED, __HIP_MEMORY_SCOPE_AGENT) < nb)
            __builtin_amdgcn_s_sleep(2);
        __threadfence();                       // acquire (inv L1)
    }
    __syncthreads();
}

struct GJob {
    const float* giA; const float* giB;
    const float* ghA; const float* ghB;
    const float* bin; const float* bhb;
    const float* ginw; const float* ginb;
    const float* ghw;  const float* ghb;
    float* cx; f16* h16; int k; int k0;
};
struct MegaArgs {
    const int* code; const int* ncode; const float* emb;
    const float* win; const float* wh;
    const float* bin_; const float* bh;
    const float* gin_w; const float* gin_b;
    const float* gh_w;  const float* gh_b;
    f16* wp; f16* h1; f16* h2;
    float* gi1; float* gi2; float* ghat1; float* ghat2;
    float* cx1; float* cx2;
};

// ---- phase bodies (verbatim r18/r20 logic, known-good) ----

__device__ void prep_task(const MegaArgs& A, int task, int t) {
    if (task < 1792) {
        int e = task * 256 + t;          // < 458752
        int ch = e & 63;
        int pos = e >> 6;                // nc*7*512 + s*512 + vox
        int vox = pos & 511;
        int tt = pos >> 9;
        int s = tt % 7, nc = tt / 7;
        int tok = (s < 5) ? A.code[(nc*5 + s)*512 + vox]
                          : A.ncode[(nc*3 + (s-5))*512 + vox];
        float x = A.emb[tok*64 + ch];
        f16 hi = (f16)x;
        A.h1[(size_t)pos*128 + ch]      = hi;
        A.h1[(size_t)pos*128 + 64 + ch] = (f16)(x - (float)hi);
    } else {
        int b = task - 1792;             // 108 = 4 tensors * 27 taps
        int tensor = b / 27, tap = b % 27;
        const float* src = ((tensor & 1) ? A.wh : A.win)
                         + (tensor >> 1) * WSTRIDE + tap * 16384;
        int co = t;
        int sw = co & 7;
        #pragma unroll
        for (int hs = 0; hs < 2; ++hs) {
            f16* dst = A.wp + (((size_t)tensor*27 + tap)*2 + hs)*16384 + co*64;
            #pragma unroll
            for (int j = 0; j < 4; ++j) {
                f16x8 hi8, lo8;
                #pragma unroll
                for (int m = 0; m < 8; ++m) {
                    float w = src[(hs*32 + j*8 + m)*256 + co] * 64.f;
                    f16 hv = (f16)w;
                    hi8[m] = hv;
                    lo8[m] = (f16)(w - (float)hv);
                }
                *(f16x8*)(dst + ((j     ^ sw))*8) = hi8;
                *(f16x8*)(dst + (((4+j) ^ sw))*8) = lo8;
            }
        }
    }
}

// One conv tile: 32-vox a-half x 64 co, K-atoms split over 8 groups
// (kb*4+wid). 3-segment hi/lo f16 MFMA, partial written to y + kb*GPART.
__device__ void conv_tile(const f16* X, const f16* W, float* Y,
                          int bx, int t, float4* smem) {
    f16* wbuf = (f16*)smem;
    const int cog = bx & 3, u = (bx >> 2) & 7, slab = (bx >> 5) & 1;
    const int ah = (bx >> 6) & 1, kb = bx >> 7;
    const int wid = t >> 6, l = t & 63;
    const int lv = (l >> 3) & 1, lw = l & 7, khi = l >> 4;

    const int gid = kb*4 + wid;
    const int g0  = (gid < 6) ? gid*7 : 42 + (gid - 6)*6;
    const int cnt = (gid < 6) ? 7 : 6;

    const f16* xbase = X + (size_t)slab * HSP;
    const f16* wjob  = W + (size_t)cog * 4096;        // + atom*16384
    f16* wmine = wbuf + wid * 4096;                   // 8KB, single-buffered

    f16x8 wreg[8];
    auto wload = [&](int k) {
        const f16* src = wjob + (size_t)k * 16384 + l * 8;
        #pragma unroll
        for (int i = 0; i < 8; ++i) wreg[i] = *(const f16x8*)(src + i * 512);
    };
    auto wstore = [&]() {
        f16* dst = wmine + l * 8;
        #pragma unroll
        for (int i = 0; i < 8; ++i) *(f16x8*)(dst + i * 512) = wreg[i];
    };

    wload(g0); wstore();

    f32x4 acc[2][4] = {};
    for (int q = 0; q < cnt; ++q) {
        const int k = g0 + q;
        if (q + 1 < cnt) wload(k + 1);
        const int tap = k >> 1, hs = k & 1;
        const int du = tap / 9, rr = tap % 9, dv = rr / 3, dw = rr % 3;
        const int uu = u + du - 1;
        const bool uok = (unsigned)uu < 8u;
        const f16* xrow[2]; bool ok[2];
        #pragma unroll
        for (int aa = 0; aa < 2; ++aa) {
            int vs = (ah*2 + aa)*2 + lv + dv - 1, ws = lw + dw - 1;
            ok[aa] = uok && (unsigned)vs < 8u && (unsigned)ws < 8u;
            xrow[aa] = xbase + ((size_t)(uu*64 + vs*8 + ws) << 7) + khi*8;
        }
        const f16* wrow = wmine + (l & 15)*64;
        const int schi = ((khi    ) ^ lw) * 8;
        const int sclo = ((4 + khi) ^ lw) * 8;
        f16x8 ahi[2], alo[2], bhi[4], blo[4];
        #pragma unroll
        for (int aa = 0; aa < 2; ++aa) {
            f16x8 v = {0,0,0,0,0,0,0,0}, v2 = v;
            if (ok[aa]) {
                v  = *(const f16x8*)(xrow[aa] + hs*32);
                v2 = *(const f16x8*)(xrow[aa] + 64 + hs*32);
            }
            ahi[aa] = v; alo[aa] = v2;
        }
        #pragma unroll
        for (int n = 0; n < 4; ++n) {
            bhi[n] = *(const f16x8*)(wrow + n*1024 + schi);
            blo[n] = *(const f16x8*)(wrow + n*1024 + sclo);
        }
        #pragma unroll
        for (int aa = 0; aa < 2; ++aa)
            #pragma unroll
            for (int n = 0; n < 4; ++n)
                acc[aa][n] = __builtin_amdgcn_mfma_f32_16x16x32_f16(
                    ahi[aa], bhi[n], acc[aa][n], 0, 0, 0);
        #pragma unroll
        for (int aa = 0; aa < 2; ++aa)
            #pragma unroll
            for (int n = 0; n < 4; ++n)
                acc[aa][n] = __builtin_amdgcn_mfma_f32_16x16x32_f16(
                    alo[aa], bhi[n], acc[aa][n], 0, 0, 0);
        #pragma unroll
        for (int aa = 0; aa < 2; ++aa)
            #pragma unroll
            for (int n = 0; n < 4; ++n)
                acc[aa][n] = __builtin_amdgcn_mfma_f32_16x16x32_f16(
                    ahi[aa], blo[n], acc[aa][n], 0, 0, 0);
        if (q + 1 < cnt) wstore();
    }

    f32x4* red = (f32x4*)smem;
    {
        f32x4* mine = red + (size_t)(wid * 64 + l) * 8;
        #pragma unroll
        for (int aa = 0; aa < 2; ++aa)
            #pragma unroll
            for (int n = 0; n < 4; ++n)
                mine[(aa * 4 + n) ^ lw] = acc[aa][n];
    }
    __syncthreads();
    {
        float* yp = Y + (size_t)kb * GPART;
        const int aa = (t >> 7) & 1, nsel = (t >> 6) & 1, ll = t & 63;
        #pragma unroll
        for (int ni = 0; ni < 2; ++ni) {
            const int n = nsel*2 + ni;
            const int ch = (aa * 4 + n) ^ (ll & 7);
            f32x4 sv = red[(0 * 64 + ll) * 8 + ch]
                     + red[(1 * 64 + ll) * 8 + ch]
                     + red[(2 * 64 + ll) * 8 + ch]
                     + red[(3 * 64 + ll) * 8 + ch];
            const int co = cog * 64 + n * 16 + (ll & 15);
            #pragma unroll
            for (int r = 0; r < 4; ++r) {
                int vox = (ah*2 + aa) * 16 + (ll >> 4) * 4 + r;
                yp[(size_t)(slab * 512 + u * 64 + vox) * 256 + co]
                    = sv[r] * 0.015625f;            // /64 (w' scale)
            }
        }
    }
    __syncthreads();    // LDS reuse guard for the next grid-strided tile
}

__device__ void gates_task(const GJob& J, int bx, int t) {
    const int wid = t >> 6, lane = t & 63;
    const int row = bx * 4 + wid;             // nc*512 + vox, < 1024
    const int nc = row >> 9, vox = row & 511;

    const float* gA = J.giA + (size_t)row*256;
    const float* gB = J.giB + (size_t)row*256;
    float a0 = gA[lane]     + gB[lane]     + J.bin[lane];
    float a1 = gA[64+lane]  + gB[64+lane]  + J.bin[64+lane];
    float a2 = gA[128+lane] + gB[128+lane] + J.bin[128+lane];
    float a3 = gA[192+lane] + gB[192+lane] + J.bin[192+lane];
    float mu1 = wred_sum(a0+a1+a2+a3) * (1.f/256.f);
    float d0=a0-mu1, d1=a1-mu1, d2=a2-mu1, d3=a3-mu1;
    float v1 = wred_sum(d0*d0+d1*d1+d2*d2+d3*d3) * (1.f/256.f);
    float rs1 = rsqrtf(v1 + 1e-5f);

    float b0, b1, b2, b3;
    if (J.k0) {
        b0 = J.bhb[lane]; b1 = J.bhb[64+lane];
        b2 = J.bhb[128+lane]; b3 = J.bhb[192+lane];
    } else {
        const float* hA = J.ghA + (size_t)row*256;
        const float* hB = J.ghB + (size_t)row*256;
        b0 = hA[lane]     + hB[lane]     + J.bhb[lane];
        b1 = hA[64+lane]  + hB[64+lane]  + J.bhb[64+lane];
        b2 = hA[128+lane] + hB[128+lane] + J.bhb[128+lane];
        b3 = hA[192+lane] + hB[192+lane] + J.bhb[192+lane];
    }
    float mu2 = wred_sum(b0+b1+b2+b3) * (1.f/256.f);
    float e0=b0-mu2, e1=b1-mu2, e2=b2-mu2, e3=b3-mu2;
    float v2 = wred_sum(e0*e0+e1*e1+e2*e2+e3*e3) * (1.f/256.f);
    float rs2 = rsqrtf(v2 + 1e-5f);

    float Ig = d0*rs1*J.ginw[lane]     + J.ginb[lane]     + e0*rs2*J.ghw[lane]     + J.ghb[lane];
    float Fg = d1*rs1*J.ginw[64+lane]  + J.ginb[64+lane]  + e1*rs2*J.ghw[64+lane]  + J.ghb[64+lane];
    float Cg = d2*rs1*J.ginw[128+lane] + J.ginb[128+lane] + e2*rs2*J.ghw[128+lane] + J.ghb[128+lane];
    float Og = d3*rs1*J.ginw[192+lane] + J.ginb[192+lane] + e3*rs2*J.ghw[192+lane] + J.ghb[192+lane];

    float c_old = J.k0 ? 0.f : J.cx[(size_t)row*64 + lane];
    float c_new = fsig(Fg)*c_old + fsig(Ig)*ftanh(Cg);
    float h_new = fsig(Og)*ftanh(c_new);
    J.cx[(size_t)row*64 + lane] = c_new;
    size_t hb = ((size_t)(nc*7 + J.k)*512 + vox)*128 + lane;
    f16 hi = (f16)h_new;
    J.h16[hb]      = hi;
    J.h16[hb + 64] = (f16)(h_new - (float)hi);
}

// ---- kernels ----

// prep (embed + wpack) -> bar -> all 7 layer-1 input convs (1792 tiles)
__global__ __launch_bounds__(256, 3) void prep_conv_kernel(MegaArgs A, int* bar, int nb)
{
    __shared__ float4 smem[2048];          // 32 KiB
    const int bid = blockIdx.x, t = threadIdx.x;
    for (int task = bid; task < 1900; task += nb) prep_task(A, task, t);
    flagbar(bar, nb);
    for (int task = bid; task < 1792; task += nb) {
        int s = task >> 8;
        conv_tile(A.h1 + (size_t)s*XSP, A.wp,
                  A.gi1 + (size_t)s*2*GPART, task & 255, t, smem);
    }
}

// one recurrence step: gates1(s) + gates2(s-1) [s>=1] -> bar ->
// convs rec1(s)/in2(s)/rec2(s-1)
__global__ __launch_bounds__(256, 3) void step_kernel(MegaArgs A, int s, int* bar, int nb)
{
    __shared__ float4 smem[2048];
    const int bid = blockIdx.x, t = threadIdx.x;

    GJob gj0, gj1; int ngj = 0;
    {
        GJob g1 = { A.gi1 + (size_t)s*2*GPART, A.gi1 + (size_t)s*2*GPART + GPART,
                    A.ghat1, A.ghat1 + GPART, A.bin_, A.bh,
                    A.gin_w, A.gin_b, A.gh_w, A.gh_b, A.cx1, A.h1, s, s == 0 };
        gj0 = g1; ngj = 1;            // s<=6 always true in this loop
    }
    if (s >= 1) {
        GJob g2 = { A.gi2, A.gi2 + GPART, A.ghat2, A.ghat2 + GPART,
                    A.bin_ + 256, A.bh + 256, A.gin_w + 256, A.gin_b + 256,
                    A.gh_w + 256, A.gh_b + 256, A.cx2, A.h2, s - 1, s == 1 };
        gj1 = g2; ngj = 2;
    }
    for (int task = bid; task < ngj*256; task += nb) {
        if ((task >> 8) == 0) gates_task(gj0, task & 255, t);
        else                  gates_task(gj1, task & 255, t);
    }

    // conv job pointer sets (scalar selects, no runtime-indexed arrays)
    const f16 *x0=nullptr,*w0=nullptr; float* y0=nullptr;
    const f16 *x1=nullptr,*w1=nullptr; float* y1=nullptr;
    const f16 *x2=nullptr,*w2=nullptr; float* y2=nullptr;
    int ncj = 0;
    if (s <= 5) { x0 = A.h1 + (size_t)s*XSP; w0 = A.wp + WPT; y0 = A.ghat1; ncj = 1; }
    {   // in2(s), s<=6 always
        const f16* x = A.h1 + (size_t)s*XSP; const f16* w = A.wp + 2*WPT; float* y = A.gi2;
        if (ncj == 0) { x0=x; w0=w; y0=y; } else { x1=x; w1=w; y1=y; }
        ++ncj;
    }
    if (s >= 1) {
        const f16* x = A.h2 + (size_t)(s-1)*XSP; const f16* w = A.wp + 3*WPT; float* y = A.ghat2;
        if (ncj == 1) { x1=x; w1=w; y1=y; } else { x2=x; w2=w; y2=y; }
        ++ncj;
    }

    flagbar(bar, nb);

    for (int task = bid; task < ncj*256; task += nb) {
        int q = task >> 8;
        const f16* xj = (q==0) ? x0 : (q==1) ? x1 : x2;
        const f16* wj = (q==0) ? w0 : (q==1) ? w1 : w2;
        float*     yj = (q==0) ? y0 : (q==1) ? y1 : y2;
        conv_tile(xj, wj, yj, task & 255, t, smem);
    }
}

// head: phase A = gates2(6) (256 blocks x 4 rows) -> bar -> phase B = head
// proper on the first 192 blocks (r18 body, one loss atomic per block).
__global__ __launch_bounds__(256) void head_kernel(MegaArgs A,
    const float* __restrict__ w1, const float* __restrict__ b1,
    const float* __restrict__ lng, const float* __restrict__ lnb,
    const float* __restrict__ w2, const float* __restrict__ b2,
    float* __restrict__ out, int* bar, int nb)
{
    {
        GJob gj = { A.gi2, A.gi2 + GPART, A.ghat2, A.ghat2 + GPART,
                    A.bin_ + 256, A.bh + 256, A.gin_w + 256, A.gin_b + 256,
                    A.gh_w + 256, A.gh_b + 256, A.cx2, A.h2, 6, 0 };
        gates_task(gj, blockIdx.x, threadIdx.x);
    }
    flagbar(bar, nb);
    if (blockIdx.x >= 192) return;

    const f16* h = A.h2;
    const int* ncode = A.ncode;
    __shared__ float hsm[16][64];
    __shared__ float zv[16][64];
    __shared__ float lg[10240];               // [512 co][16 vox] stride 20
    __shared__ float lsum[16];
    const int blk = blockIdx.x;               // 192 = n(2) x sn(3) x vg(32)
    const int n = blk / 96;
    const int sn = (blk / 32) % 3;
    const int vox0 = (blk & 31) * 16;
    const int t = threadIdx.x, wid = t >> 6, lane = t & 63;

    for (int idx = t; idx < 1024; idx += 256) {
        int vr = idx >> 6, ch = idx & 63;
        const f16* hv = h + (size_t)((n*7 + sn + 4)*512 + vox0 + vr)*128;
        hsm[vr][ch] = (float)hv[ch] + (float)hv[64 + ch];
    }
    __syncthreads();

    float yva[4], yvb[4];
    #pragma unroll
    for (int r = 0; r < 4; ++r) { yva[r] = b1[lane]; yvb[r] = 0.f; }
    for (int kk = 0; kk < 64; kk += 2) {
        float w1a = w1[kk*64 + lane], w1b = w1[(kk+1)*64 + lane];
        #pragma unroll
        for (int r = 0; r < 4; ++r) {
            yva[r] = fmaf(hsm[wid*4 + r][kk],     w1a, yva[r]);
            yvb[r] = fmaf(hsm[wid*4 + r][kk + 1], w1b, yvb[r]);
        }
    }
    #pragma unroll
    for (int r = 0; r < 4; ++r) {
        float yv = yva[r] + yvb[r];
        float mu = wred_sum(yv) * (1.f/64.f);
        float d = yv - mu;
        float var = wred_sum(d*d) * (1.f/64.f);
        float ln = d * rsqrtf(var + 1e-5f) * lng[lane] + lnb[lane];
        zv[wid*4 + r][lane] = 0.5f * ln * (1.f + erff(ln * 0.70710678118654752f));
    }
    __syncthreads();

    float l[4][8];
    #pragma unroll
    for (int r = 0; r < 4; ++r)
        #pragma unroll
        for (int j = 0; j < 8; ++j) l[r][j] = b2[j*64 + lane];
    for (int kk = 0; kk < 64; ++kk) {
        float wv[8];
        #pragma unroll
        for (int j = 0; j < 8; ++j) wv[j] = w2[kk*512 + j*64 + lane];
        #pragma unroll
        for (int r = 0; r < 4; ++r) {
            float zz = zv[wid*4 + r][kk];
            #pragma unroll
            for (int j = 0; j < 8; ++j) l[r][j] = fmaf(zz, wv[j], l[r][j]);
        }
    }
    #pragma unroll
    for (int r = 0; r < 4; ++r)
        #pragma unroll
        for (int j = 0; j < 8; ++j)
            lg[(j*64 + lane)*20 + wid*4 + r] = l[r][j];

    #pragma unroll
    for (int r = 0; r < 4; ++r) {
        float m = l[r][0]; int mi = lane;
        #pragma unroll
        for (int j = 1; j < 8; ++j)
            if (l[r][j] > m) { m = l[r][j]; mi = j*64 + lane; }
        #pragma unroll
        for (int o = 32; o > 0; o >>= 1) {
            float om = __shfl_down(m, o, 64);
            int   oi = __shfl_down(mi, o, 64);
            if (om > m || (om == m && oi < mi)) { m = om; mi = oi; }
        }
        float maxv = __shfl(m, 0, 64);
        int   maxi = __shfl(mi, 0, 64);
        float es = 0.f;
        #pragma unroll
        for (int j = 0; j < 8; ++j) es += __expf(l[r][j] - maxv);
        float sum = wred_sum(es);
        if (lane == 0) {
            int vox = vox0 + wid*4 + r;
            int target = ncode[(n*3 + sn)*512 + vox];
            float logp = lg[target*20 + wid*4 + r] - maxv - __logf(sum);
            lsum[wid*4 + r] = -logp * (1.f/3072.f);
            out[1572865 + (n*3 + sn)*512 + vox] = (float)maxi;
        }
    }

    __syncthreads();
    if (t == 0) {
        float s = 0.f;
        #pragma unroll
        for (int i = 0; i < 16; ++i) s += lsum[i];
        atomicAdd(out + 1572864, s);
    }
    for (int e = t; e < 2048; e += 256) {
        int co = e >> 2, p = e & 3;
        int base = co*20 + p*4;
        float4 o4 = { lg[base], lg[base+1], lg[base+2], lg[base+3] };
        *(float4*)(out + (size_t)((n*512 + co)*3 + sn)*512 + vox0 + p*4) = o4;
    }
}

extern "C" void kernel_launch(void* const* d_in, const int* in_sizes, int n_in,
                              void* d_out, int out_size, void* d_ws, size_t ws_size,
                              hipStream_t stream) {
    (void)in_sizes; (void)n_in; (void)out_size; (void)ws_size;
    const int*   code  = (const int*)d_in[0];
    const int*   ncode = (const int*)d_in[1];
    const float* emb   = (const float*)d_in[2];
    const float* win   = (const float*)d_in[3];
    const float* bin_  = (const float*)d_in[4];
    const float* gin_w = (const float*)d_in[5];
    const float* gin_b = (const float*)d_in[6];
    const float* wh    = (const float*)d_in[7];
    const float* bh    = (const float*)d_in[8];
    const float* gh_w  = (const float*)d_in[9];
    const float* gh_b  = (const float*)d_in[10];
    const float* w1    = (const float*)d_in[11];
    const float* b1    = (const float*)d_in[12];
    const float* ln_g  = (const float*)d_in[13];
    const float* ln_b  = (const float*)d_in[14];
    const float* w2    = (const float*)d_in[15];
    const float* b2    = (const float*)d_in[16];
    float* out = (float*)d_out;

    float* base  = (float*)d_ws;
    f16*   wp    = (f16*)base;                    // 1,769,472 floats
    f16*   h1    = (f16*)(base + 1769472);        // 458,752 floats
    f16*   h2    = (f16*)(base + 2228224);        // 458,752 floats
    float* gi1   = base + 2686976;                // 7 slots x 2 partials
    float* gi2   = gi1 + 7*2*GPART;               // base + 6356992
    float* ghat1 = gi2 + 2*GPART;                 // base + 6881280
    float* ghat2 = ghat1 + 2*GPART;               // base + 7405568
    float* cx1   = ghat2 + 2*GPART;               // base + 7929856
    float* cx2   = cx1 + 65536;                   // base + 7995392
    int*   bar   = (int*)(base + 8060928);        // 16 counters

    MegaArgs A = { code, ncode, emb, win, wh, bin_, bh,
                   gin_w, gin_b, gh_w, gh_b,
                   wp, h1, h2, gi1, gi2, ghat1, ghat2, cx1, cx2 };

    static int nb_prep = 0, nb_step = 0;
    if (nb_prep == 0) {
        int occ = 0;
        if (hipOccupancyMaxActiveBlocksPerMultiprocessor(&occ, prep_conv_kernel,
                256, 0) != hipSuccess || occ < 1) occ = 1;
        if (occ > 3) occ = 3;                 // guaranteed-resident clamp
        nb_prep = occ * 256;
        occ = 0;
        if (hipOccupancyMaxActiveBlocksPerMultiprocessor(&occ, step_kernel,
                256, 0) != hipSuccess || occ < 1) occ = 1;
        if (occ > 3) occ = 3;
        nb_step = occ * 256;
    }

    hipMemsetAsync(out + 1572864, 0, sizeof(float), stream);   // loss accumulator
    hipMemsetAsync(bar, 0, 16 * sizeof(int), stream);          // barrier counters

    prep_conv_kernel<<<nb_prep, 256, 0, stream>>>(A, bar + 0, nb_prep);
    for (int s = 0; s <= 6; ++s)
        step_kernel<<<nb_step, 256, 0, stream>>>(A, s, bar + 1 + s, nb_step);
    head_kernel<<<256, 256, 0, stream>>>(A, w1, b1, ln_g, ln_b, w2, b2,
                                         out, bar + 8, 256);
}

// Round 9
// 319.635 us; speedup vs baseline: 2.7171x; 1.5203x over previous
//
#include <hip/hip_runtime.h>

// r23: barriers abandoned (r20/r22: grid-barrier ~20-30us each regardless of
// poll type -> worse than launch boundaries). r18 launch skeleton restored
// (known 305us) with two changes driven by the weight-BW model:
//  (a) conv tile M=32 -> M=64 (full u-plane, acc[4][4], r17-proven mapping):
//      weight traffic per job 55 -> 27.6 MB. K-split kb=4 (16 groups x 3-4
//      atoms) keeps grid 256/job; epilogue reduces in two 32KB LDS passes;
//      gates sums 4 partials. __launch_bounds__(256,2).
//  (b) all 7 recurrence-free layer-1 input convs hoisted into ONE batched
//      dispatch (win0 L2-warm across jobs); loop conv launches ncj<=3.
// Numerics: 3-segment hi/lo f16 MFMA, verbatim (absmax 0.00390625 expected).

typedef _Float16 f16;
typedef _Float16 f16x8 __attribute__((ext_vector_type(8)));
typedef float    f32x4 __attribute__((ext_vector_type(4)));

#define WSTRIDE 442368   // fp32 weight elements per layer: 27*64*256
#define WPT     884736   // halfs per packed tensor: 54*256*64
#define XSP     65536    // halfs per s-slab of h: 512*128
#define HSP     458752   // halfs per nc of h: 7*512*128
#define GPART   262144   // floats per conv partial buffer: 2*512*256

__device__ __forceinline__ float wred_sum(float v) {
    #pragma unroll
    for (int o = 32; o > 0; o >>= 1) v += __shfl_down(v, o, 64);
    return __shfl(v, 0, 64);
}
__device__ __forceinline__ float fsig(float x)  { return 1.f / (1.f + __expf(-x)); }
__device__ __forceinline__ float ftanh(float x) { return 1.f - 2.f / (__expf(2.f*x) + 1.f); }

// prep: blocks [0,1792) embed h1 hi/lo; blocks [1792,1900) pack weights.
__global__ __launch_bounds__(256) void prep_kernel(
    const int* __restrict__ code, const int* __restrict__ ncode,
    const float* __restrict__ emb, f16* __restrict__ h,
    const float* __restrict__ win, const float* __restrict__ wh,
    f16* __restrict__ wp)
{
    if (blockIdx.x < 1792) {
        int e = blockIdx.x * 256 + threadIdx.x;   // < 458752
        int ch = e & 63;
        int pos = e >> 6;            // nc*7*512 + s*512 + vox
        int vox = pos & 511;
        int t = pos >> 9;
        int s = t % 7, nc = t / 7;
        int tok = (s < 5) ? code[(nc*5 + s)*512 + vox]
                          : ncode[(nc*3 + (s-5))*512 + vox];
        float x = emb[tok*64 + ch];
        f16 hi = (f16)x;
        h[(size_t)pos*128 + ch]      = hi;
        h[(size_t)pos*128 + 64 + ch] = (f16)(x - (float)hi);
    } else {
        // pack: src [27][64 ci][256 co] fp32 -> per K-atom (tap, ci-half)
        // [54][256 co][8 chunks][8] f16; hi chunk j at (j ^ (co&7)), lo at
        // ((4+j) ^ (co&7)); values x64. Order: win0, wh0, win1, wh1.
        int b = blockIdx.x - 1792;        // 108 = 4 tensors * 27 taps
        int tensor = b / 27, tap = b % 27;
        const float* src = ((tensor & 1) ? wh : win) + (tensor >> 1) * WSTRIDE
                         + tap * 16384;
        int co = threadIdx.x;
        int sw = co & 7;
        #pragma unroll
        for (int hs = 0; hs < 2; ++hs) {
            f16* dst = wp + (((size_t)tensor*27 + tap)*2 + hs)*16384 + co*64;
            #pragma unroll
            for (int j = 0; j < 4; ++j) {
                f16x8 hi8, lo8;
                #pragma unroll
                for (int m = 0; m < 8; ++m) {
                    float w = src[(hs*32 + j*8 + m)*256 + co] * 64.f;
                    f16 hv = (f16)w;
                    hi8[m] = hv;
                    lo8[m] = (f16)(w - (float)hv);
                }
                *(f16x8*)(dst + ((j     ^ sw))*8) = hi8;
                *(f16x8*)(dst + (((4+j) ^ sw))*8) = lo8;
            }
        }
    }
}

struct MJob { const f16* x; const f16* w; float* y; };
struct MJobs { MJob j[8]; };

// One 3x3x3 SAME conv job (Cin=64 -> Cout=256), implicit GEMM, 3-segment
// hi/lo f16 MFMA. grid.x = 256/job: [kb(4)|slab(2)|u(8)|cog(4)].
// Block = full 64-vox u-plane x 64 co, K-atoms split over 16 groups
// (kb*4+wid: groups 0-5 have 4 atoms, 6-15 have 3; total 54). Each wave
// stages its atom's cog-slice (8KB) into a private single-buffered LDS
// region. Epilogue: two 32KB reduce passes; partial -> y + kb*GPART.
__global__ __launch_bounds__(256, 2) void conv_mfma_kernel(MJobs js)
{
    const MJob J = js.j[blockIdx.y];
    __shared__ float4 smem[2048];          // 32 KiB
    f16* wbuf = (f16*)smem;

    const int bx = blockIdx.x;
    const int cog = bx & 3, u = (bx >> 2) & 7, slab = (bx >> 5) & 1, kb = bx >> 6;
    const int t = threadIdx.x, wid = t >> 6, l = t & 63;
    const int lv = (l >> 3) & 1, lw = l & 7, khi = l >> 4;

    const int gid = kb*4 + wid;                       // 16 K-groups
    const int g0  = (gid < 6) ? gid*4 : 24 + (gid - 6)*3;
    const int cnt = (gid < 6) ? 4 : 3;

    const f16* xbase = J.x + (size_t)slab * HSP;
    const f16* wjob  = J.w + (size_t)cog * 4096;      // + atom*16384
    f16* wmine = wbuf + wid * 4096;                   // 8KB, single-buffered

    f16x8 wreg[8];
    auto wload = [&](int k) {
        const f16* src = wjob + (size_t)k * 16384 + l * 8;
        #pragma unroll
        for (int i = 0; i < 8; ++i) wreg[i] = *(const f16x8*)(src + i * 512);
    };
    auto wstore = [&]() {
        f16* dst = wmine + l * 8;
        #pragma unroll
        for (int i = 0; i < 8; ++i) *(f16x8*)(dst + i * 512) = wreg[i];
    };

    wload(g0); wstore();

    f32x4 acc[4][4] = {};                 // [a: vox 16-tile][n: co 16-tile]
    for (int q = 0; q < cnt; ++q) {
        const int k = g0 + q;
        if (q + 1 < cnt) wload(k + 1);
        const int tap = k >> 1, hs = k & 1;
        const int du = tap / 9, rr = tap % 9, dv = rr / 3, dw = rr % 3;
        const int uu = u + du - 1;
        const bool uok = (unsigned)uu < 8u;
        const f16* xrow[4]; bool ok[4];
        #pragma unroll
        for (int a = 0; a < 4; ++a) {               // vox = a*16 + (l&15)
            int vs = a*2 + lv + dv - 1, ws = lw + dw - 1;
            ok[a] = uok && (unsigned)vs < 8u && (unsigned)ws < 8u;
            xrow[a] = xbase + ((size_t)(uu*64 + vs*8 + ws) << 7) + khi*8;
        }
        const f16* wrow = wmine + (l & 15)*64;
        const int schi = ((khi    ) ^ lw) * 8;
        const int sclo = ((4 + khi) ^ lw) * 8;
        f16x8 ahi[4], alo[4], bhi[4], blo[4];
        #pragma unroll
        for (int a = 0; a < 4; ++a) {
            f16x8 v = {0,0,0,0,0,0,0,0}, v2 = v;
            if (ok[a]) {
                v  = *(const f16x8*)(xrow[a] + hs*32);
                v2 = *(const f16x8*)(xrow[a] + 64 + hs*32);
            }
            ahi[a] = v; alo[a] = v2;
        }
        #pragma unroll
        for (int n = 0; n < 4; ++n) {
            bhi[n] = *(const f16x8*)(wrow + n*1024 + schi);
            blo[n] = *(const f16x8*)(wrow + n*1024 + sclo);
        }
        #pragma unroll
        for (int a = 0; a < 4; ++a)
            #pragma unroll
            for (int n = 0; n < 4; ++n)
                acc[a][n] = __builtin_amdgcn_mfma_f32_16x16x32_f16(
                    ahi[a], bhi[n], acc[a][n], 0, 0, 0);
        #pragma unroll
        for (int a = 0; a < 4; ++a)
            #pragma unroll
            for (int n = 0; n < 4; ++n)
                acc[a][n] = __builtin_amdgcn_mfma_f32_16x16x32_f16(
                    alo[a], bhi[n], acc[a][n], 0, 0, 0);
        #pragma unroll
        for (int a = 0; a < 4; ++a)
            #pragma unroll
            for (int n = 0; n < 4; ++n)
                acc[a][n] = __builtin_amdgcn_mfma_f32_16x16x32_f16(
                    ahi[a], blo[n], acc[a][n], 0, 0, 0);
        if (q + 1 < cnt) wstore();
    }

    // Two-pass 4-way K-reduce (acc is 16 f32x4/lane = 64KB/block total;
    // 32KB LDS -> halves). Each wave dumps into its OWN 8KB region.
    f32x4* red = (f32x4*)smem;
    float* yp = J.y + (size_t)kb * GPART;
    #pragma unroll
    for (int half = 0; half < 2; ++half) {
        {
            f32x4* mine = red + (size_t)(wid * 64 + l) * 8;
            #pragma unroll
            for (int aa = 0; aa < 2; ++aa)
                #pragma unroll
                for (int n = 0; n < 4; ++n)
                    mine[(aa * 4 + n) ^ lw] = acc[half*2 + aa][n];
        }
        __syncthreads();
        {
            const int aa = (t >> 7) & 1, nsel = (t >> 6) & 1, ll = t & 63;
            #pragma unroll
            for (int ni = 0; ni < 2; ++ni) {
                const int n = nsel*2 + ni;
                const int ch = (aa * 4 + n) ^ (ll & 7);
                f32x4 sv = red[(0 * 64 + ll) * 8 + ch]
                         + red[(1 * 64 + ll) * 8 + ch]
                         + red[(2 * 64 + ll) * 8 + ch]
                         + red[(3 * 64 + ll) * 8 + ch];
                const int co = cog * 64 + n * 16 + (ll & 15);
                #pragma unroll
                for (int r = 0; r < 4; ++r) {       // D row = 4*(ll>>4)+r
                    int vox = (half*2 + aa) * 16 + (ll >> 4) * 4 + r;
                    yp[(size_t)(slab * 512 + u * 64 + vox) * 256 + co]
                        = sv[r] * 0.015625f;        // /64 (w' scale)
                }
            }
        }
        __syncthreads();
    }
}

// Dual-LN LSTM cell (fp32). Sums FOUR conv partials + bias per path.
struct GJob {
    const float* gi;   // 4 partials at stride GPART
    const float* gh;   // 4 partials at stride GPART (ignored if k0)
    const float* bin; const float* bhb;
    const float* ginw; const float* ginb;
    const float* ghw;  const float* ghb;
    float* cx; f16* h16; int k; int k0;
};
__global__ __launch_bounds__(256) void gates_step_kernel(GJob ja, GJob jb)
{
    const GJob J = (blockIdx.y == 0) ? ja : jb;
    const int wid = threadIdx.x >> 6, lane = threadIdx.x & 63;
    const int row = blockIdx.x * 4 + wid;     // nc*512 + vox, < 1024
    const int nc = row >> 9, vox = row & 511;

    const float* g = J.gi + (size_t)row*256;
    float a0, a1, a2, a3;
    {
        float s0 = g[lane]             + g[GPART+lane]
                 + g[2*GPART+lane]     + g[3*GPART+lane];
        float s1 = g[64+lane]          + g[GPART+64+lane]
                 + g[2*GPART+64+lane]  + g[3*GPART+64+lane];
        float s2 = g[128+lane]         + g[GPART+128+lane]
                 + g[2*GPART+128+lane] + g[3*GPART+128+lane];
        float s3 = g[192+lane]         + g[GPART+192+lane]
                 + g[2*GPART+192+lane] + g[3*GPART+192+lane];
        a0 = s0 + J.bin[lane];       a1 = s1 + J.bin[64+lane];
        a2 = s2 + J.bin[128+lane];   a3 = s3 + J.bin[192+lane];
    }
    float mu1 = wred_sum(a0+a1+a2+a3) * (1.f/256.f);
    float d0=a0-mu1, d1=a1-mu1, d2=a2-mu1, d3=a3-mu1;
    float v1 = wred_sum(d0*d0+d1*d1+d2*d2+d3*d3) * (1.f/256.f);
    float rs1 = rsqrtf(v1 + 1e-5f);

    float b0, b1, b2, b3;
    if (J.k0) {
        b0 = J.bhb[lane]; b1 = J.bhb[64+lane];
        b2 = J.bhb[128+lane]; b3 = J.bhb[192+lane];
    } else {
        const float* hh = J.gh + (size_t)row*256;
        b0 = hh[lane]             + hh[GPART+lane]
           + hh[2*GPART+lane]     + hh[3*GPART+lane]     + J.bhb[lane];
        b1 = hh[64+lane]          + hh[GPART+64+lane]
           + hh[2*GPART+64+lane]  + hh[3*GPART+64+lane]  + J.bhb[64+lane];
        b2 = hh[128+lane]         + hh[GPART+128+lane]
           + hh[2*GPART+128+lane] + hh[3*GPART+128+lane] + J.bhb[128+lane];
        b3 = hh[192+lane]         + hh[GPART+192+lane]
           + hh[2*GPART+192+lane] + hh[3*GPART+192+lane] + J.bhb[192+lane];
    }
    float mu2 = wred_sum(b0+b1+b2+b3) * (1.f/256.f);
    float e0=b0-mu2, e1=b1-mu2, e2=b2-mu2, e3=b3-mu2;
    float v2 = wred_sum(e0*e0+e1*e1+e2*e2+e3*e3) * (1.f/256.f);
    float rs2 = rsqrtf(v2 + 1e-5f);

    float Ig = d0*rs1*J.ginw[lane]     + J.ginb[lane]     + e0*rs2*J.ghw[lane]     + J.ghb[lane];
    float Fg = d1*rs1*J.ginw[64+lane]  + J.ginb[64+lane]  + e1*rs2*J.ghw[64+lane]  + J.ghb[64+lane];
    float Cg = d2*rs1*J.ginw[128+lane] + J.ginb[128+lane] + e2*rs2*J.ghw[128+lane] + J.ghb[128+lane];
    float Og = d3*rs1*J.ginw[192+lane] + J.ginb[192+lane] + e3*rs2*J.ghw[192+lane] + J.ghb[192+lane];

    float c_old = J.k0 ? 0.f : J.cx[(size_t)row*64 + lane];
    float c_new = fsig(Fg)*c_old + fsig(Ig)*ftanh(Cg);
    float h_new = fsig(Og)*ftanh(c_new);
    J.cx[(size_t)row*64 + lane] = c_new;
    size_t hb = ((size_t)(nc*7 + J.k)*512 + vox)*128 + lane;
    f16 hi = (f16)h_new;
    J.h16[hb]      = hi;
    J.h16[hb + 64] = (f16)(h_new - (float)hi);
}

// Head: r18's known-good version (192 blocks x 16 vox, one loss atomic/block).
__global__ __launch_bounds__(256) void head_kernel(
    const f16* __restrict__ h,        // [2][7][512][128] hi/lo
    const float* __restrict__ w1, const float* __restrict__ b1,
    const float* __restrict__ lng, const float* __restrict__ lnb,
    const float* __restrict__ w2, const float* __restrict__ b2,
    const int* __restrict__ ncode,
    float* __restrict__ out)
{
    __shared__ float hsm[16][64];
    __shared__ float zv[16][64];
    __shared__ float lg[10240];               // [512 co][16 vox] stride 20
    __shared__ float lsum[16];
    const int blk = blockIdx.x;               // 192 = n(2) x sn(3) x vg(32)
    const int n = blk / 96;
    const int sn = (blk / 32) % 3;
    const int vox0 = (blk & 31) * 16;
    const int t = threadIdx.x, wid = t >> 6, lane = t & 63;

    for (int idx = t; idx < 1024; idx += 256) {
        int vr = idx >> 6, ch = idx & 63;
        const f16* hv = h + (size_t)((n*7 + sn + 4)*512 + vox0 + vr)*128;
        hsm[vr][ch] = (float)hv[ch] + (float)hv[64 + ch];
    }
    __syncthreads();

    float yva[4], yvb[4];
    #pragma unroll
    for (int r = 0; r < 4; ++r) { yva[r] = b1[lane]; yvb[r] = 0.f; }
    for (int kk = 0; kk < 64; kk += 2) {
        float w1a = w1[kk*64 + lane], w1b = w1[(kk+1)*64 + lane];
        #pragma unroll
        for (int r = 0; r < 4; ++r) {
            yva[r] = fmaf(hsm[wid*4 + r][kk],     w1a, yva[r]);
            yvb[r] = fmaf(hsm[wid*4 + r][kk + 1], w1b, yvb[r]);
        }
    }
    #pragma unroll
    for (int r = 0; r < 4; ++r) {
        float yv = yva[r] + yvb[r];
        float mu = wred_sum(yv) * (1.f/64.f);
        float d = yv - mu;
        float var = wred_sum(d*d) * (1.f/64.f);
        float ln = d * rsqrtf(var + 1e-5f) * lng[lane] + lnb[lane];
        zv[wid*4 + r][lane] = 0.5f * ln * (1.f + erff(ln * 0.70710678118654752f));
    }
    __syncthreads();

    float l[4][8];
    #pragma unroll
    for (int r = 0; r < 4; ++r)
        #pragma unroll
        for (int j = 0; j < 8; ++j) l[r][j] = b2[j*64 + lane];
    for (int kk = 0; kk < 64; ++kk) {
        float wv[8];
        #pragma unroll
        for (int j = 0; j < 8; ++j) wv[j] = w2[kk*512 + j*64 + lane];
        #pragma unroll
        for (int r = 0; r < 4; ++r) {
            float zz = zv[wid*4 + r][kk];
            #pragma unroll
            for (int j = 0; j < 8; ++j) l[r][j] = fmaf(zz, wv[j], l[r][j]);
        }
    }
    #pragma unroll
    for (int r = 0; r < 4; ++r)
        #pragma unroll
        for (int j = 0; j < 8; ++j)
            lg[(j*64 + lane)*20 + wid*4 + r] = l[r][j];

    #pragma unroll
    for (int r = 0; r < 4; ++r) {
        float m = l[r][0]; int mi = lane;
        #pragma unroll
        for (int j = 1; j < 8; ++j)
            if (l[r][j] > m) { m = l[r][j]; mi = j*64 + lane; }
        #pragma unroll
        for (int o = 32; o > 0; o >>= 1) {
            float om = __shfl_down(m, o, 64);
            int   oi = __shfl_down(mi, o, 64);
            if (om > m || (om == m && oi < mi)) { m = om; mi = oi; }
        }
        float maxv = __shfl(m, 0, 64);
        int   maxi = __shfl(mi, 0, 64);
        float es = 0.f;
        #pragma unroll
        for (int j = 0; j < 8; ++j) es += __expf(l[r][j] - maxv);
        float sum = wred_sum(es);
        if (lane == 0) {
            int vox = vox0 + wid*4 + r;
            int target = ncode[(n*3 + sn)*512 + vox];
            float logp = lg[target*20 + wid*4 + r] - maxv - __logf(sum);
            lsum[wid*4 + r] = -logp * (1.f/3072.f);
            out[1572865 + (n*3 + sn)*512 + vox] = (float)maxi;
        }
    }

    __syncthreads();
    if (t == 0) {
        float s = 0.f;
        #pragma unroll
        for (int i = 0; i < 16; ++i) s += lsum[i];
        atomicAdd(out + 1572864, s);
    }
    for (int e = t; e < 2048; e += 256) {
        int co = e >> 2, p = e & 3;
        int base = co*20 + p*4;
        float4 o4 = { lg[base], lg[base+1], lg[base+2], lg[base+3] };
        *(float4*)(out + (size_t)((n*512 + co)*3 + sn)*512 + vox0 + p*4) = o4;
    }
}

extern "C" void kernel_launch(void* const* d_in, const int* in_sizes, int n_in,
                              void* d_out, int out_size, void* d_ws, size_t ws_size,
                              hipStream_t stream) {
    (void)in_sizes; (void)n_in; (void)out_size; (void)ws_size;
    const int*   code  = (const int*)d_in[0];
    const int*   ncode = (const int*)d_in[1];
    const float* emb   = (const float*)d_in[2];
    const float* win   = (const float*)d_in[3];
    const float* bin_  = (const float*)d_in[4];
    const float* gin_w = (const float*)d_in[5];
    const float* gin_b = (const float*)d_in[6];
    const float* wh    = (const float*)d_in[7];
    const float* bh    = (const float*)d_in[8];
    const float* gh_w  = (const float*)d_in[9];
    const float* gh_b  = (const float*)d_in[10];
    const float* w1    = (const float*)d_in[11];
    const float* b1    = (const float*)d_in[12];
    const float* ln_g  = (const float*)d_in[13];
    const float* ln_b  = (const float*)d_in[14];
    const float* w2    = (const float*)d_in[15];
    const float* b2    = (const float*)d_in[16];
    float* out = (float*)d_out;

    float* base  = (float*)d_ws;
    f16*   wp    = (f16*)base;                    // 1,769,472 floats
    f16*   h1    = (f16*)(base + 1769472);        // 458,752 floats
    f16*   h2    = (f16*)(base + 2228224);        // 458,752 floats
    float* gi1   = base + 2686976;                // 7 slots x 4 partials x GPART
    float* gi2   = gi1 + 7*4*(size_t)GPART;       // 4 partials
    float* ghat1 = gi2 + 4*(size_t)GPART;
    float* ghat2 = ghat1 + 4*(size_t)GPART;
    float* cx1   = ghat2 + 4*(size_t)GPART;       // [2][512][64]
    float* cx2   = cx1 + 65536;                   // end ~13.3M floats (~53MB)

    const f16* win0 = wp;
    const f16* wh0  = wp + WPT;
    const f16* win1 = wp + 2*WPT;
    const f16* wh1  = wp + 3*WPT;

    hipMemsetAsync(out + 1572864, 0, sizeof(float), stream);   // loss accumulator
    prep_kernel<<<1900, 256, 0, stream>>>(code, ncode, emb, h1, win, wh, wp);

    // all 7 recurrence-free layer-1 input convs, one batched dispatch
    {
        MJobs js{};
        for (int s = 0; s < 7; ++s)
            js.j[s] = { h1 + (size_t)s*XSP, win0, gi1 + (size_t)s*4*GPART };
        conv_mfma_kernel<<<dim3(256, 7), 256, 0, stream>>>(js);
    }

    for (int s = 0; s <= 7; ++s) {
        // ---- gates: gates1(s) [s<=6], gates2(s-1) [s>=1] ----
        GJob g1 = { gi1 + (size_t)s*4*GPART, ghat1, bin_, bh,
                    gin_w, gin_b, gh_w, gh_b, cx1, h1, s, s == 0 };
        GJob g2 = { gi2, ghat2, bin_ + 256, bh + 256,
                    gin_w + 256, gin_b + 256, gh_w + 256, gh_b + 256,
                    cx2, h2, s - 1, s == 1 };
        if (s == 0)
            gates_step_kernel<<<dim3(256, 1), 256, 0, stream>>>(g1, g1);
        else if (s <= 6)
            gates_step_kernel<<<dim3(256, 2), 256, 0, stream>>>(g1, g2);
        else
            gates_step_kernel<<<dim3(256, 1), 256, 0, stream>>>(g2, g2);

        // ---- convs: rec1(s) [s<=5], in2(s) [s<=6], rec2(s-1) [1<=s<=6] ----
        MJobs js{}; int nj = 0;
        if (s <= 5) js.j[nj++] = { h1 + (size_t)s*XSP,     wh0,  ghat1 };
        if (s <= 6) js.j[nj++] = { h1 + (size_t)s*XSP,     win1, gi2 };
        if (s >= 1 && s <= 6)
                    js.j[nj++] = { h2 + (size_t)(s-1)*XSP, wh1,  ghat2 };
        if (nj > 0)
            conv_mfma_kernel<<<dim3(256, nj), 256, 0, stream>>>(js);
    }

    head_kernel<<<192, 256, 0, stream>>>(h2, w1, b1, ln_g, ln_b, w2, b2, ncode, out);
}

// Round 10
// 305.678 us; speedup vs baseline: 2.8411x; 1.0457x over previous
//
#include <hip/hip_runtime.h>

// r24: r18 skeleton (305us proven) + two targeted fixes:
//  (a) head: 192 -> 768 blocks (4 vox/block, 1 vox/wave). r23 counters showed
//      head at 43us with 6.6% occupancy = CU starvation (0.75 blocks/CU).
//      Loss now per-block -> workspace array + 1-wave finalize kernel (zero
//      global atomics). Same per-vox math.
//  (b) conv/gates: r18 M=32/kb=2/2-partial versions verbatim (r23's M=64
//      conv was a net +15us). Keep the batched 7-job in1 dispatch.
// Numerics: 3-segment hi/lo f16 MFMA (absmax 0.00390625 expected).

typedef _Float16 f16;
typedef _Float16 f16x8 __attribute__((ext_vector_type(8)));
typedef float    f32x4 __attribute__((ext_vector_type(4)));

#define WSTRIDE 442368   // fp32 weight elements per layer: 27*64*256
#define WPT     884736   // halfs per packed tensor: 54*256*64
#define XSP     65536    // halfs per s-slab of h: 512*128
#define HSP     458752   // halfs per nc of h: 7*512*128
#define GPART   262144   // floats per conv partial buffer: 2*512*256

__device__ __forceinline__ float wred_sum(float v) {
    #pragma unroll
    for (int o = 32; o > 0; o >>= 1) v += __shfl_down(v, o, 64);
    return __shfl(v, 0, 64);
}
__device__ __forceinline__ float fsig(float x)  { return 1.f / (1.f + __expf(-x)); }
__device__ __forceinline__ float ftanh(float x) { return 1.f - 2.f / (__expf(2.f*x) + 1.f); }

// prep: blocks [0,1792) embed h1 hi/lo; blocks [1792,1900) pack weights.
__global__ __launch_bounds__(256) void prep_kernel(
    const int* __restrict__ code, const int* __restrict__ ncode,
    const float* __restrict__ emb, f16* __restrict__ h,
    const float* __restrict__ win, const float* __restrict__ wh,
    f16* __restrict__ wp)
{
    if (blockIdx.x < 1792) {
        int e = blockIdx.x * 256 + threadIdx.x;   // < 458752
        int ch = e & 63;
        int pos = e >> 6;            // nc*7*512 + s*512 + vox
        int vox = pos & 511;
        int t = pos >> 9;
        int s = t % 7, nc = t / 7;
        int tok = (s < 5) ? code[(nc*5 + s)*512 + vox]
                          : ncode[(nc*3 + (s-5))*512 + vox];
        float x = emb[tok*64 + ch];
        f16 hi = (f16)x;
        h[(size_t)pos*128 + ch]      = hi;
        h[(size_t)pos*128 + 64 + ch] = (f16)(x - (float)hi);
    } else {
        // pack: src [27][64 ci][256 co] fp32 -> per K-atom (tap, ci-half)
        // [54][256 co][8 chunks][8] f16; hi chunk j at (j ^ (co&7)), lo at
        // ((4+j) ^ (co&7)); values x64. Order: win0, wh0, win1, wh1.
        int b = blockIdx.x - 1792;        // 108 = 4 tensors * 27 taps
        int tensor = b / 27, tap = b % 27;
        const float* src = ((tensor & 1) ? wh : win) + (tensor >> 1) * WSTRIDE
                         + tap * 16384;
        int co = threadIdx.x;
        int sw = co & 7;
        #pragma unroll
        for (int hs = 0; hs < 2; ++hs) {
            f16* dst = wp + (((size_t)tensor*27 + tap)*2 + hs)*16384 + co*64;
            #pragma unroll
            for (int j = 0; j < 4; ++j) {
                f16x8 hi8, lo8;
                #pragma unroll
                for (int m = 0; m < 8; ++m) {
                    float w = src[(hs*32 + j*8 + m)*256 + co] * 64.f;
                    f16 hv = (f16)w;
                    hi8[m] = hv;
                    lo8[m] = (f16)(w - (float)hv);
                }
                *(f16x8*)(dst + ((j     ^ sw))*8) = hi8;
                *(f16x8*)(dst + (((4+j) ^ sw))*8) = lo8;
            }
        }
    }
}

struct MJob { const f16* x; const f16* w; float* y; };
struct MJobs { MJob j[8]; };

// One 3x3x3 SAME conv job (Cin=64 -> Cout=256), implicit GEMM, 3-segment
// hi/lo f16 MFMA. grid.x = 256/job: [kb(2)|ah(2)|slab(2)|u(8)|cog(4)].
// Block = 32-vox a-half x 64 co; 54 K-atoms split over 8 groups (kb*4+wid,
// {7x6,6x2}); each wave stages its atom tile (8KB, single-buffered) into a
// private region. One barrier; in-block 4-way K-reduce; partial written to
// y + kb*GPART (no bias). [r18 version, verbatim]
__global__ __launch_bounds__(256, 3) void conv_mfma_kernel(MJobs js)
{
    const MJob J = js.j[blockIdx.y];
    __shared__ float4 smem[2048];          // 32 KiB
    f16* wbuf = (f16*)smem;

    const int bx = blockIdx.x;
    const int cog = bx & 3, u = (bx >> 2) & 7, slab = (bx >> 5) & 1;
    const int ah = (bx >> 6) & 1, kb = bx >> 7;
    const int t = threadIdx.x, wid = t >> 6, l = t & 63;
    const int lv = (l >> 3) & 1, lw = l & 7, khi = l >> 4;

    const int gid = kb*4 + wid;
    const int g0  = (gid < 6) ? gid*7 : 42 + (gid - 6)*6;
    const int cnt = (gid < 6) ? 7 : 6;

    const f16* xbase = J.x + (size_t)slab * HSP;
    const f16* wjob  = J.w + (size_t)cog * 4096;      // + atom*16384
    f16* wmine = wbuf + wid * 4096;                   // 8KB, single-buffered

    f16x8 wreg[8];
    auto wload = [&](int k) {
        const f16* src = wjob + (size_t)k * 16384 + l * 8;
        #pragma unroll
        for (int i = 0; i < 8; ++i) wreg[i] = *(const f16x8*)(src + i * 512);
    };
    auto wstore = [&]() {
        f16* dst = wmine + l * 8;
        #pragma unroll
        for (int i = 0; i < 8; ++i) *(f16x8*)(dst + i * 512) = wreg[i];
    };

    wload(g0); wstore();

    f32x4 acc[2][4] = {};
    for (int q = 0; q < cnt; ++q) {
        const int k = g0 + q;
        if (q + 1 < cnt) wload(k + 1);
        const int tap = k >> 1, hs = k & 1;
        const int du = tap / 9, rr = tap % 9, dv = rr / 3, dw = rr % 3;
        const int uu = u + du - 1;
        const bool uok = (unsigned)uu < 8u;
        const f16* xrow[2]; bool ok[2];
        #pragma unroll
        for (int aa = 0; aa < 2; ++aa) {
            int vs = (ah*2 + aa)*2 + lv + dv - 1, ws = lw + dw - 1;
            ok[aa] = uok && (unsigned)vs < 8u && (unsigned)ws < 8u;
            xrow[aa] = xbase + ((size_t)(uu*64 + vs*8 + ws) << 7) + khi*8;
        }
        const f16* wrow = wmine + (l & 15)*64;
        const int schi = ((khi    ) ^ lw) * 8;
        const int sclo = ((4 + khi) ^ lw) * 8;
        f16x8 ahi[2], alo[2], bhi[4], blo[4];
        #pragma unroll
        for (int aa = 0; aa < 2; ++aa) {
            f16x8 v = {0,0,0,0,0,0,0,0}, v2 = v;
            if (ok[aa]) {
                v  = *(const f16x8*)(xrow[aa] + hs*32);
                v2 = *(const f16x8*)(xrow[aa] + 64 + hs*32);
            }
            ahi[aa] = v; alo[aa] = v2;
        }
        #pragma unroll
        for (int n = 0; n < 4; ++n) {
            bhi[n] = *(const f16x8*)(wrow + n*1024 + schi);
            blo[n] = *(const f16x8*)(wrow + n*1024 + sclo);
        }
        #pragma unroll
        for (int aa = 0; aa < 2; ++aa)
            #pragma unroll
            for (int n = 0; n < 4; ++n)
                acc[aa][n] = __builtin_amdgcn_mfma_f32_16x16x32_f16(
                    ahi[aa], bhi[n], acc[aa][n], 0, 0, 0);
        #pragma unroll
        for (int aa = 0; aa < 2; ++aa)
            #pragma unroll
            for (int n = 0; n < 4; ++n)
                acc[aa][n] = __builtin_amdgcn_mfma_f32_16x16x32_f16(
                    alo[aa], bhi[n], acc[aa][n], 0, 0, 0);
        #pragma unroll
        for (int aa = 0; aa < 2; ++aa)
            #pragma unroll
            for (int n = 0; n < 4; ++n)
                acc[aa][n] = __builtin_amdgcn_mfma_f32_16x16x32_f16(
                    ahi[aa], blo[n], acc[aa][n], 0, 0, 0);
        if (q + 1 < cnt) wstore();
    }

    f32x4* red = (f32x4*)smem;
    {
        f32x4* mine = red + (size_t)(wid * 64 + l) * 8;
        #pragma unroll
        for (int aa = 0; aa < 2; ++aa)
            #pragma unroll
            for (int n = 0; n < 4; ++n)
                mine[(aa * 4 + n) ^ lw] = acc[aa][n];
    }
    __syncthreads();
    {
        float* yp = J.y + (size_t)kb * GPART;
        const int aa = (t >> 7) & 1, nsel = (t >> 6) & 1, ll = t & 63;
        #pragma unroll
        for (int ni = 0; ni < 2; ++ni) {
            const int n = nsel*2 + ni;
            const int ch = (aa * 4 + n) ^ (ll & 7);
            f32x4 sv = red[(0 * 64 + ll) * 8 + ch]
                     + red[(1 * 64 + ll) * 8 + ch]
                     + red[(2 * 64 + ll) * 8 + ch]
                     + red[(3 * 64 + ll) * 8 + ch];
            const int co = cog * 64 + n * 16 + (ll & 15);
            #pragma unroll
            for (int r = 0; r < 4; ++r) {
                int vox = (ah*2 + aa) * 16 + (ll >> 4) * 4 + r;
                yp[(size_t)(slab * 512 + u * 64 + vox) * 256 + co]
                    = sv[r] * 0.015625f;            // /64 (w' scale)
            }
        }
    }
}

// Dual-LN LSTM cell (fp32). Sums the two conv partials + bias per path.
// [r18 version, verbatim]
struct GJob {
    const float* giA; const float* giB;
    const float* ghA; const float* ghB;
    const float* bin; const float* bhb;
    const float* ginw; const float* ginb;
    const float* ghw;  const float* ghb;
    float* cx; f16* h16; int k; int k0;
};
__global__ __launch_bounds__(256) void gates_step_kernel(GJob ja, GJob jb)
{
    const GJob J = (blockIdx.y == 0) ? ja : jb;
    const int wid = threadIdx.x >> 6, lane = threadIdx.x & 63;
    const int row = blockIdx.x * 4 + wid;     // nc*512 + vox, < 1024
    const int nc = row >> 9, vox = row & 511;

    const float* gA = J.giA + (size_t)row*256;
    const float* gB = J.giB + (size_t)row*256;
    float a0 = gA[lane]     + gB[lane]     + J.bin[lane];
    float a1 = gA[64+lane]  + gB[64+lane]  + J.bin[64+lane];
    float a2 = gA[128+lane] + gB[128+lane] + J.bin[128+lane];
    float a3 = gA[192+lane] + gB[192+lane] + J.bin[192+lane];
    float mu1 = wred_sum(a0+a1+a2+a3) * (1.f/256.f);
    float d0=a0-mu1, d1=a1-mu1, d2=a2-mu1, d3=a3-mu1;
    float v1 = wred_sum(d0*d0+d1*d1+d2*d2+d3*d3) * (1.f/256.f);
    float rs1 = rsqrtf(v1 + 1e-5f);

    float b0, b1, b2, b3;
    if (J.k0) {
        b0 = J.bhb[lane]; b1 = J.bhb[64+lane];
        b2 = J.bhb[128+lane]; b3 = J.bhb[192+lane];
    } else {
        const float* hA = J.ghA + (size_t)row*256;
        const float* hB = J.ghB + (size_t)row*256;
        b0 = hA[lane]     + hB[lane]     + J.bhb[lane];
        b1 = hA[64+lane]  + hB[64+lane]  + J.bhb[64+lane];
        b2 = hA[128+lane] + hB[128+lane] + J.bhb[128+lane];
        b3 = hA[192+lane] + hB[192+lane] + J.bhb[192+lane];
    }
    float mu2 = wred_sum(b0+b1+b2+b3) * (1.f/256.f);
    float e0=b0-mu2, e1=b1-mu2, e2=b2-mu2, e3=b3-mu2;
    float v2 = wred_sum(e0*e0+e1*e1+e2*e2+e3*e3) * (1.f/256.f);
    float rs2 = rsqrtf(v2 + 1e-5f);

    float Ig = d0*rs1*J.ginw[lane]     + J.ginb[lane]     + e0*rs2*J.ghw[lane]     + J.ghb[lane];
    float Fg = d1*rs1*J.ginw[64+lane]  + J.ginb[64+lane]  + e1*rs2*J.ghw[64+lane]  + J.ghb[64+lane];
    float Cg = d2*rs1*J.ginw[128+lane] + J.ginb[128+lane] + e2*rs2*J.ghw[128+lane] + J.ghb[128+lane];
    float Og = d3*rs1*J.ginw[192+lane] + J.ginb[192+lane] + e3*rs2*J.ghw[192+lane] + J.ghb[192+lane];

    float c_old = J.k0 ? 0.f : J.cx[(size_t)row*64 + lane];
    float c_new = fsig(Fg)*c_old + fsig(Ig)*ftanh(Cg);
    float h_new = fsig(Og)*ftanh(c_new);
    J.cx[(size_t)row*64 + lane] = c_new;
    size_t hb = ((size_t)(nc*7 + J.k)*512 + vox)*128 + lane;
    f16 hi = (f16)h_new;
    J.h16[hb]      = hi;
    J.h16[hb + 64] = (f16)(h_new - (float)hi);
}

// Head: 768 blocks x 4 vox (1 vox per wave). Per-block loss to workspace
// (no atomics); finalized by loss_fin_kernel.
__global__ __launch_bounds__(256) void head_kernel(
    const f16* __restrict__ h,        // [2][7][512][128] hi/lo
    const float* __restrict__ w1, const float* __restrict__ b1,
    const float* __restrict__ lng, const float* __restrict__ lnb,
    const float* __restrict__ w2, const float* __restrict__ b2,
    const int* __restrict__ ncode,
    float* __restrict__ out, float* __restrict__ lossb)
{
    __shared__ float hsm[4][64];
    __shared__ float zv[4][64];
    __shared__ float lg[4][512];
    __shared__ float lsum[4];
    const int blk = blockIdx.x;               // 768 = n(2) x sn(3) x vg(128)
    const int n = blk / 384;
    const int sn = (blk / 128) % 3;
    const int vox0 = (blk & 127) * 4;
    const int t = threadIdx.x, wid = t >> 6, lane = t & 63;
    const int vox = vox0 + wid;
    const f16* hv = h + (size_t)((n*7 + sn + 4)*512 + vox)*128;

    // own-wave staging (no cross-wave reads until the score-write phase)
    hsm[wid][lane] = (float)hv[lane] + (float)hv[64 + lane];

    // GEMV1 (h @ w1 + b1), dual accumulators
    float yva = b1[lane], yvb = 0.f;
    for (int kk = 0; kk < 64; kk += 2) {
        yva = fmaf(hsm[wid][kk],     w1[kk*64 + lane],     yva);
        yvb = fmaf(hsm[wid][kk + 1], w1[(kk+1)*64 + lane], yvb);
    }
    float yv = yva + yvb;
    float mu = wred_sum(yv) * (1.f/64.f);
    float d = yv - mu;
    float var = wred_sum(d*d) * (1.f/64.f);
    float ln = d * rsqrtf(var + 1e-5f) * lng[lane] + lnb[lane];
    zv[wid][lane] = 0.5f * ln * (1.f + erff(ln * 0.70710678118654752f));

    // GEMM2: logits[512] for this wave's vox; 8 independent chains
    float l[8];
    #pragma unroll
    for (int j = 0; j < 8; ++j) l[j] = b2[j*64 + lane];
    for (int kk = 0; kk < 64; ++kk) {
        float zz = zv[wid][kk];
        #pragma unroll
        for (int j = 0; j < 8; ++j)
            l[j] = fmaf(zz, w2[kk*512 + j*64 + lane], l[j]);
    }
    #pragma unroll
    for (int j = 0; j < 8; ++j) lg[wid][j*64 + lane] = l[j];

    // softmax / argmax / loss (wave-local)
    float m = l[0]; int mi = lane;
    #pragma unroll
    for (int j = 1; j < 8; ++j)
        if (l[j] > m) { m = l[j]; mi = j*64 + lane; }
    #pragma unroll
    for (int o = 32; o > 0; o >>= 1) {
        float om = __shfl_down(m, o, 64);
        int   oi = __shfl_down(mi, o, 64);
        if (om > m || (om == m && oi < mi)) { m = om; mi = oi; }
    }
    float maxv = __shfl(m, 0, 64);
    int   maxi = __shfl(mi, 0, 64);
    float es = 0.f;
    #pragma unroll
    for (int j = 0; j < 8; ++j) es += __expf(l[j] - maxv);
    float sum = wred_sum(es);
    if (lane == 0) {
        int target = ncode[(n*3 + sn)*512 + vox];
        float logp = lg[wid][target] - maxv - __logf(sum);
        lsum[wid] = -logp * (1.f/3072.f);
        out[1572865 + (n*3 + sn)*512 + vox] = (float)maxi;
    }

    __syncthreads();
    if (t == 0) lossb[blk] = lsum[0] + lsum[1] + lsum[2] + lsum[3];
    // score writes: float4 over the 4 vox per co
    for (int co = t; co < 512; co += 256) {
        float4 o4 = { lg[0][co], lg[1][co], lg[2][co], lg[3][co] };
        *(float4*)(out + (size_t)((n*512 + co)*3 + sn)*512 + vox0) = o4;
    }
}

__global__ void loss_fin_kernel(const float* __restrict__ lossb,
                                float* __restrict__ out)
{
    float s = 0.f;
    for (int i = threadIdx.x; i < 768; i += 64) s += lossb[i];
    s = wred_sum(s);
    if (threadIdx.x == 0) out[1572864] = s;
}

extern "C" void kernel_launch(void* const* d_in, const int* in_sizes, int n_in,
                              void* d_out, int out_size, void* d_ws, size_t ws_size,
                              hipStream_t stream) {
    (void)in_sizes; (void)n_in; (void)out_size; (void)ws_size;
    const int*   code  = (const int*)d_in[0];
    const int*   ncode = (const int*)d_in[1];
    const float* emb   = (const float*)d_in[2];
    const float* win   = (const float*)d_in[3];
    const float* bin_  = (const float*)d_in[4];
    const float* gin_w = (const float*)d_in[5];
    const float* gin_b = (const float*)d_in[6];
    const float* wh    = (const float*)d_in[7];
    const float* bh    = (const float*)d_in[8];
    const float* gh_w  = (const float*)d_in[9];
    const float* gh_b  = (const float*)d_in[10];
    const float* w1    = (const float*)d_in[11];
    const float* b1    = (const float*)d_in[12];
    const float* ln_g  = (const float*)d_in[13];
    const float* ln_b  = (const float*)d_in[14];
    const float* w2    = (const float*)d_in[15];
    const float* b2    = (const float*)d_in[16];
    float* out = (float*)d_out;

    float* base  = (float*)d_ws;
    f16*   wp    = (f16*)base;                    // 1,769,472 floats
    f16*   h1    = (f16*)(base + 1769472);        // 458,752 floats
    f16*   h2    = (f16*)(base + 2228224);        // 458,752 floats
    float* gi1   = base + 2686976;                // 7 slots x 2 partials x GPART
    float* gi2   = gi1 + 7*2*(size_t)GPART;       // base + 6,356,992
    float* ghat1 = gi2 + 2*GPART;                 // base + 6,881,280
    float* ghat2 = ghat1 + 2*GPART;               // base + 7,405,568
    float* cx1   = ghat2 + 2*GPART;               // base + 7,929,856
    float* cx2   = cx1 + 65536;                   // base + 7,995,392
    float* lossb = base + 8060928;                // 768 floats

    const f16* win0 = wp;
    const f16* wh0  = wp + WPT;
    const f16* win1 = wp + 2*WPT;
    const f16* wh1  = wp + 3*WPT;

    prep_kernel<<<1900, 256, 0, stream>>>(code, ncode, emb, h1, win, wh, wp);

    // all 7 recurrence-free layer-1 input convs, one batched dispatch
    {
        MJobs js{};
        for (int s = 0; s < 7; ++s)
            js.j[s] = { h1 + (size_t)s*XSP, win0, gi1 + (size_t)s*2*GPART };
        conv_mfma_kernel<<<dim3(256, 7), 256, 0, stream>>>(js);
    }

    for (int s = 0; s <= 7; ++s) {
        // ---- gates: gates1(s) [s<=6], gates2(s-1) [s>=1] ----
        GJob g1 = { gi1 + (size_t)s*2*GPART, gi1 + (size_t)s*2*GPART + GPART,
                    ghat1, ghat1 + GPART, bin_, bh,
                    gin_w, gin_b, gh_w, gh_b, cx1, h1, s, s == 0 };
        GJob g2 = { gi2, gi2 + GPART, ghat2, ghat2 + GPART, bin_ + 256, bh + 256,
                    gin_w + 256, gin_b + 256, gh_w + 256, gh_b + 256,
                    cx2, h2, s - 1, s == 1 };
        if (s == 0)
            gates_step_kernel<<<dim3(256, 1), 256, 0, stream>>>(g1, g1);
        else if (s <= 6)
            gates_step_kernel<<<dim3(256, 2), 256, 0, stream>>>(g1, g2);
        else
            gates_step_kernel<<<dim3(256, 1), 256, 0, stream>>>(g2, g2);

        // ---- convs: rec1(s) [s<=5], in2(s) [s<=6], rec2(s-1) [1<=s<=6] ----
        MJobs js{}; int nj = 0;
        if (s <= 5) js.j[nj++] = { h1 + (size_t)s*XSP,     wh0,  ghat1 };
        if (s <= 6) js.j[nj++] = { h1 + (size_t)s*XSP,     win1, gi2 };
        if (s >= 1 && s <= 6)
                    js.j[nj++] = { h2 + (size_t)(s-1)*XSP, wh1,  ghat2 };
        if (nj > 0)
            conv_mfma_kernel<<<dim3(256, nj), 256, 0, stream>>>(js);
    }

    head_kernel<<<768, 256, 0, stream>>>(h2, w1, b1, ln_g, ln_b, w2, b2,
                                         ncode, out, lossb);
    loss_fin_kernel<<<1, 64, 0, stream>>>(lossb, out);
}

// Round 11
// 304.370 us; speedup vs baseline: 2.8533x; 1.0043x over previous
//
#include <hip/hip_runtime.h>

// r25: r24 (305us) minus dispatch fat:
//  (a) embed deleted: in1-batch convs gather emb16[code[vox]] directly
//      (embed-h1 was only read by in1; rec1/in2 read the GATED h1). prep is
//      now 236 blocks: weight pack + 512-row emb16 hi/lo table.
//  (b) head absorbs gates2(6): sn==2 blocks compute the slot-6 LSTM row
//      inline per vox (identical math; h2/cx2 writes were dead). The s=7
//      gates-only dispatch is gone.
//  (c) conv __launch_bounds__(256,4) (VGPR 68 << 128 cap) for the 1792-block
//      in1 batch.
// Conv tile / gates math verbatim r18/r24. absmax expected 0.00390625.

typedef _Float16 f16;
typedef _Float16 f16x8 __attribute__((ext_vector_type(8)));
typedef float    f32x4 __attribute__((ext_vector_type(4)));

#define WSTRIDE 442368   // fp32 weight elements per layer: 27*64*256
#define WPT     884736   // halfs per packed tensor: 54*256*64
#define XSP     65536    // halfs per s-slab of h: 512*128
#define HSP     458752   // halfs per nc of h: 7*512*128
#define GPART   262144   // floats per conv partial buffer: 2*512*256

__device__ __forceinline__ float wred_sum(float v) {
    #pragma unroll
    for (int o = 32; o > 0; o >>= 1) v += __shfl_down(v, o, 64);
    return __shfl(v, 0, 64);
}
__device__ __forceinline__ float fsig(float x)  { return 1.f / (1.f + __expf(-x)); }
__device__ __forceinline__ float ftanh(float x) { return 1.f - 2.f / (__expf(2.f*x) + 1.f); }

// prep: blocks [0,108) pack weights; [108,236) build emb16 hi/lo table.
__global__ __launch_bounds__(256) void prep_kernel(
    const float* __restrict__ emb, f16* __restrict__ emb16,
    const float* __restrict__ win, const float* __restrict__ wh,
    f16* __restrict__ wp)
{
    if (blockIdx.x < 108) {
        // pack: src [27][64 ci][256 co] fp32 -> per K-atom (tap, ci-half)
        // [54][256 co][8 chunks][8] f16; hi chunk j at (j ^ (co&7)), lo at
        // ((4+j) ^ (co&7)); values x64. Order: win0, wh0, win1, wh1.
        int b = blockIdx.x;               // 108 = 4 tensors * 27 taps
        int tensor = b / 27, tap = b % 27;
        const float* src = ((tensor & 1) ? wh : win) + (tensor >> 1) * WSTRIDE
                         + tap * 16384;
        int co = threadIdx.x;
        int sw = co & 7;
        #pragma unroll
        for (int hs = 0; hs < 2; ++hs) {
            f16* dst = wp + (((size_t)tensor*27 + tap)*2 + hs)*16384 + co*64;
            #pragma unroll
            for (int j = 0; j < 4; ++j) {
                f16x8 hi8, lo8;
                #pragma unroll
                for (int m = 0; m < 8; ++m) {
                    float w = src[(hs*32 + j*8 + m)*256 + co] * 64.f;
                    f16 hv = (f16)w;
                    hi8[m] = hv;
                    lo8[m] = (f16)(w - (float)hv);
                }
                *(f16x8*)(dst + ((j     ^ sw))*8) = hi8;
                *(f16x8*)(dst + (((4+j) ^ sw))*8) = lo8;
            }
        }
    } else {
        int e = (blockIdx.x - 108) * 256 + threadIdx.x;   // < 32768
        int ch = e & 63, tok = e >> 6;
        float x = emb[tok*64 + ch];
        f16 hi = (f16)x;
        emb16[tok*128 + ch]      = hi;
        emb16[tok*128 + 64 + ch] = (f16)(x - (float)hi);
    }
}

struct MJob { const f16* x; const f16* w; float* y;
              const int* toks; int tokStride; };
struct MJobs { MJob j[8]; };

// One 3x3x3 SAME conv job (Cin=64 -> Cout=256), implicit GEMM, 3-segment
// hi/lo f16 MFMA. grid.x = 256/job: [kb(2)|ah(2)|slab(2)|u(8)|cog(4)].
// Block = 32-vox a-half x 64 co; 54 K-atoms split over 8 groups (kb*4+wid,
// {7x6,6x2}); each wave stages its atom tile (8KB, single-buffered) into a
// private region. If J.toks != null, x is gathered: emb16[toks[vox]] (used
// by the upfront layer-1 input convs; tokens+table are L2-hot).
__global__ __launch_bounds__(256, 4) void conv_mfma_kernel(MJobs js)
{
    const MJob J = js.j[blockIdx.y];
    __shared__ float4 smem[2048];          // 32 KiB
    f16* wbuf = (f16*)smem;

    const int bx = blockIdx.x;
    const int cog = bx & 3, u = (bx >> 2) & 7, slab = (bx >> 5) & 1;
    const int ah = (bx >> 6) & 1, kb = bx >> 7;
    const int t = threadIdx.x, wid = t >> 6, l = t & 63;
    const int lv = (l >> 3) & 1, lw = l & 7, khi = l >> 4;

    const int gid = kb*4 + wid;
    const int g0  = (gid < 6) ? gid*7 : 42 + (gid - 6)*6;
    const int cnt = (gid < 6) ? 7 : 6;

    const bool gather = (J.toks != nullptr);
    const f16* xbase = J.x + (gather ? 0 : (size_t)slab * HSP);
    const int* tbase = gather ? (J.toks + slab * J.tokStride) : nullptr;
    const f16* wjob  = J.w + (size_t)cog * 4096;      // + atom*16384
    f16* wmine = wbuf + wid * 4096;                   // 8KB, single-buffered

    f16x8 wreg[8];
    auto wload = [&](int k) {
        const f16* src = wjob + (size_t)k * 16384 + l * 8;
        #pragma unroll
        for (int i = 0; i < 8; ++i) wreg[i] = *(const f16x8*)(src + i * 512);
    };
    auto wstore = [&]() {
        f16* dst = wmine + l * 8;
        #pragma unroll
        for (int i = 0; i < 8; ++i) *(f16x8*)(dst + i * 512) = wreg[i];
    };

    wload(g0); wstore();

    f32x4 acc[2][4] = {};
    for (int q = 0; q < cnt; ++q) {
        const int k = g0 + q;
        if (q + 1 < cnt) wload(k + 1);
        const int tap = k >> 1, hs = k & 1;
        const int du = tap / 9, rr = tap % 9, dv = rr / 3, dw = rr % 3;
        const int uu = u + du - 1;
        const bool uok = (unsigned)uu < 8u;
        const f16* xrow[2]; bool ok[2];
        #pragma unroll
        for (int aa = 0; aa < 2; ++aa) {
            int vs = (ah*2 + aa)*2 + lv + dv - 1, ws = lw + dw - 1;
            ok[aa] = uok && (unsigned)vs < 8u && (unsigned)ws < 8u;
            int voxidx = uu*64 + vs*8 + ws;
            if (gather) {
                int tok = 0;
                if (ok[aa]) tok = tbase[voxidx];
                xrow[aa] = xbase + (size_t)tok*128 + khi*8;
            } else {
                xrow[aa] = xbase + ((size_t)voxidx << 7) + khi*8;
            }
        }
        const f16* wrow = wmine + (l & 15)*64;
        const int schi = ((khi    ) ^ lw) * 8;
        const int sclo = ((4 + khi) ^ lw) * 8;
        f16x8 ahi[2], alo[2], bhi[4], blo[4];
        #pragma unroll
        for (int aa = 0; aa < 2; ++aa) {
            f16x8 v = {0,0,0,0,0,0,0,0}, v2 = v;
            if (ok[aa]) {
                v  = *(const f16x8*)(xrow[aa] + hs*32);
                v2 = *(const f16x8*)(xrow[aa] + 64 + hs*32);
            }
            ahi[aa] = v; alo[aa] = v2;
        }
        #pragma unroll
        for (int n = 0; n < 4; ++n) {
            bhi[n] = *(const f16x8*)(wrow + n*1024 + schi);
            blo[n] = *(const f16x8*)(wrow + n*1024 + sclo);
        }
        #pragma unroll
        for (int aa = 0; aa < 2; ++aa)
            #pragma unroll
            for (int n = 0; n < 4; ++n)
                acc[aa][n] = __builtin_amdgcn_mfma_f32_16x16x32_f16(
                    ahi[aa], bhi[n], acc[aa][n], 0, 0, 0);
        #pragma unroll
        for (int aa = 0; aa < 2; ++aa)
            #pragma unroll
            for (int n = 0; n < 4; ++n)
                acc[aa][n] = __builtin_amdgcn_mfma_f32_16x16x32_f16(
                    alo[aa], bhi[n], acc[aa][n], 0, 0, 0);
        #pragma unroll
        for (int aa = 0; aa < 2; ++aa)
            #pragma unroll
            for (int n = 0; n < 4; ++n)
                acc[aa][n] = __builtin_amdgcn_mfma_f32_16x16x32_f16(
                    ahi[aa], blo[n], acc[aa][n], 0, 0, 0);
        if (q + 1 < cnt) wstore();
    }

    f32x4* red = (f32x4*)smem;
    {
        f32x4* mine = red + (size_t)(wid * 64 + l) * 8;
        #pragma unroll
        for (int aa = 0; aa < 2; ++aa)
            #pragma unroll
            for (int n = 0; n < 4; ++n)
                mine[(aa * 4 + n) ^ lw] = acc[aa][n];
    }
    __syncthreads();
    {
        float* yp = J.y + (size_t)kb * GPART;
        const int aa = (t >> 7) & 1, nsel = (t >> 6) & 1, ll = t & 63;
        #pragma unroll
        for (int ni = 0; ni < 2; ++ni) {
            const int n = nsel*2 + ni;
            const int ch = (aa * 4 + n) ^ (ll & 7);
            f32x4 sv = red[(0 * 64 + ll) * 8 + ch]
                     + red[(1 * 64 + ll) * 8 + ch]
                     + red[(2 * 64 + ll) * 8 + ch]
                     + red[(3 * 64 + ll) * 8 + ch];
            const int co = cog * 64 + n * 16 + (ll & 15);
            #pragma unroll
            for (int r = 0; r < 4; ++r) {
                int vox = (ah*2 + aa) * 16 + (ll >> 4) * 4 + r;
                yp[(size_t)(slab * 512 + u * 64 + vox) * 256 + co]
                    = sv[r] * 0.015625f;            // /64 (w' scale)
            }
        }
    }
}

// Dual-LN LSTM cell (fp32). Sums the two conv partials + bias per path.
struct GJob {
    const float* giA; const float* giB;
    const float* ghA; const float* ghB;
    const float* bin; const float* bhb;
    const float* ginw; const float* ginb;
    const float* ghw;  const float* ghb;
    float* cx; f16* h16; int k; int k0;
};
__global__ __launch_bounds__(256) void gates_step_kernel(GJob ja, GJob jb)
{
    const GJob J = (blockIdx.y == 0) ? ja : jb;
    const int wid = threadIdx.x >> 6, lane = threadIdx.x & 63;
    const int row = blockIdx.x * 4 + wid;     // nc*512 + vox, < 1024
    const int nc = row >> 9, vox = row & 511;

    const float* gA = J.giA + (size_t)row*256;
    const float* gB = J.giB + (size_t)row*256;
    float a0 = gA[lane]     + gB[lane]     + J.bin[lane];
    float a1 = gA[64+lane]  + gB[64+lane]  + J.bin[64+lane];
    float a2 = gA[128+lane] + gB[128+lane] + J.bin[128+lane];
    float a3 = gA[192+lane] + gB[192+lane] + J.bin[192+lane];
    float mu1 = wred_sum(a0+a1+a2+a3) * (1.f/256.f);
    float d0=a0-mu1, d1=a1-mu1, d2=a2-mu1, d3=a3-mu1;
    float v1 = wred_sum(d0*d0+d1*d1+d2*d2+d3*d3) * (1.f/256.f);
    float rs1 = rsqrtf(v1 + 1e-5f);

    float b0, b1, b2, b3;
    if (J.k0) {
        b0 = J.bhb[lane]; b1 = J.bhb[64+lane];
        b2 = J.bhb[128+lane]; b3 = J.bhb[192+lane];
    } else {
        const float* hA = J.ghA + (size_t)row*256;
        const float* hB = J.ghB + (size_t)row*256;
        b0 = hA[lane]     + hB[lane]     + J.bhb[lane];
        b1 = hA[64+lane]  + hB[64+lane]  + J.bhb[64+lane];
        b2 = hA[128+lane] + hB[128+lane] + J.bhb[128+lane];
        b3 = hA[192+lane] + hB[192+lane] + J.bhb[192+lane];
    }
    float mu2 = wred_sum(b0+b1+b2+b3) * (1.f/256.f);
    float e0=b0-mu2, e1=b1-mu2, e2=b2-mu2, e3=b3-mu2;
    float v2 = wred_sum(e0*e0+e1*e1+e2*e2+e3*e3) * (1.f/256.f);
    float rs2 = rsqrtf(v2 + 1e-5f);

    float Ig = d0*rs1*J.ginw[lane]     + J.ginb[lane]     + e0*rs2*J.ghw[lane]     + J.ghb[lane];
    float Fg = d1*rs1*J.ginw[64+lane]  + J.ginb[64+lane]  + e1*rs2*J.ghw[64+lane]  + J.ghb[64+lane];
    float Cg = d2*rs1*J.ginw[128+lane] + J.ginb[128+lane] + e2*rs2*J.ghw[128+lane] + J.ghb[128+lane];
    float Og = d3*rs1*J.ginw[192+lane] + J.ginb[192+lane] + e3*rs2*J.ghw[192+lane] + J.ghb[192+lane];

    float c_old = J.k0 ? 0.f : J.cx[(size_t)row*64 + lane];
    float c_new = fsig(Fg)*c_old + fsig(Ig)*ftanh(Cg);
    float h_new = fsig(Og)*ftanh(c_new);
    J.cx[(size_t)row*64 + lane] = c_new;
    size_t hb = ((size_t)(nc*7 + J.k)*512 + vox)*128 + lane;
    f16 hi = (f16)h_new;
    J.h16[hb]      = hi;
    J.h16[hb + 64] = (f16)(h_new - (float)hi);
}

// Head: 768 blocks x 4 vox (1 vox per wave). sn==2 blocks compute the
// slot-6 gates2 row INLINE (same math as gates_step; h2/cx2 writes dead).
// Per-block loss to workspace; finalized by loss_fin_kernel.
__global__ __launch_bounds__(256) void head_kernel(
    const f16* __restrict__ h,        // [2][7][512][128] hi/lo
    const float* __restrict__ w1, const float* __restrict__ b1,
    const float* __restrict__ lng, const float* __restrict__ lnb,
    const float* __restrict__ w2, const float* __restrict__ b2,
    const int* __restrict__ ncode,
    float* __restrict__ out, float* __restrict__ lossb, GJob g2)
{
    __shared__ float hsm[4][64];
    __shared__ float zv[4][64];
    __shared__ float lg[4][512];
    __shared__ float lsum[4];
    const int blk = blockIdx.x;               // 768 = n(2) x sn(3) x vg(128)
    const int n = blk / 384;
    const int sn = (blk / 128) % 3;
    const int vox0 = (blk & 127) * 4;
    const int t = threadIdx.x, wid = t >> 6, lane = t & 63;
    const int vox = vox0 + wid;

    if (sn == 2) {
        // inline gates2(6) for this wave's vox (row = n*512 + vox)
        const int row = n*512 + vox;
        const float* gA = g2.giA + (size_t)row*256;
        const float* gB = g2.giB + (size_t)row*256;
        float a0 = gA[lane]     + gB[lane]     + g2.bin[lane];
        float a1 = gA[64+lane]  + gB[64+lane]  + g2.bin[64+lane];
        float a2 = gA[128+lane] + gB[128+lane] + g2.bin[128+lane];
        float a3 = gA[192+lane] + gB[192+lane] + g2.bin[192+lane];
        float mu1 = wred_sum(a0+a1+a2+a3) * (1.f/256.f);
        float d0=a0-mu1, d1=a1-mu1, d2=a2-mu1, d3=a3-mu1;
        float v1 = wred_sum(d0*d0+d1*d1+d2*d2+d3*d3) * (1.f/256.f);
        float rs1 = rsqrtf(v1 + 1e-5f);

        const float* hA = g2.ghA + (size_t)row*256;
        const float* hB = g2.ghB + (size_t)row*256;
        float b0v = hA[lane]     + hB[lane]     + g2.bhb[lane];
        float b1v = hA[64+lane]  + hB[64+lane]  + g2.bhb[64+lane];
        float b2v = hA[128+lane] + hB[128+lane] + g2.bhb[128+lane];
        float b3v = hA[192+lane] + hB[192+lane] + g2.bhb[192+lane];
        float mu2 = wred_sum(b0v+b1v+b2v+b3v) * (1.f/256.f);
        float e0=b0v-mu2, e1=b1v-mu2, e2=b2v-mu2, e3=b3v-mu2;
        float v2 = wred_sum(e0*e0+e1*e1+e2*e2+e3*e3) * (1.f/256.f);
        float rs2 = rsqrtf(v2 + 1e-5f);

        float Ig = d0*rs1*g2.ginw[lane]     + g2.ginb[lane]     + e0*rs2*g2.ghw[lane]     + g2.ghb[lane];
        float Fg = d1*rs1*g2.ginw[64+lane]  + g2.ginb[64+lane]  + e1*rs2*g2.ghw[64+lane]  + g2.ghb[64+lane];
        float Cg = d2*rs1*g2.ginw[128+lane] + g2.ginb[128+lane] + e2*rs2*g2.ghw[128+lane] + g2.ghb[128+lane];
        float Og = d3*rs1*g2.ginw[192+lane] + g2.ginb[192+lane] + e3*rs2*g2.ghw[192+lane] + g2.ghb[192+lane];

        float c_old = g2.cx[(size_t)row*64 + lane];
        float c_new = fsig(Fg)*c_old + fsig(Ig)*ftanh(Cg);
        hsm[wid][lane] = fsig(Og)*ftanh(c_new);
    } else {
        const f16* hv = h + (size_t)((n*7 + sn + 4)*512 + vox)*128;
        hsm[wid][lane] = (float)hv[lane] + (float)hv[64 + lane];
    }

    // GEMV1 (h @ w1 + b1), dual accumulators
    float yva = b1[lane], yvb = 0.f;
    for (int kk = 0; kk < 64; kk += 2) {
        yva = fmaf(hsm[wid][kk],     w1[kk*64 + lane],     yva);
        yvb = fmaf(hsm[wid][kk + 1], w1[(kk+1)*64 + lane], yvb);
    }
    float yv = yva + yvb;
    float mu = wred_sum(yv) * (1.f/64.f);
    float d = yv - mu;
    float var = wred_sum(d*d) * (1.f/64.f);
    float ln = d * rsqrtf(var + 1e-5f) * lng[lane] + lnb[lane];
    zv[wid][lane] = 0.5f * ln * (1.f + erff(ln * 0.70710678118654752f));

    // GEMM2: logits[512] for this wave's vox; 8 independent chains
    float l[8];
    #pragma unroll
    for (int j = 0; j < 8; ++j) l[j] = b2[j*64 + lane];
    for (int kk = 0; kk < 64; ++kk) {
        float zz = zv[wid][kk];
        #pragma unroll
        for (int j = 0; j < 8; ++j)
            l[j] = fmaf(zz, w2[kk*512 + j*64 + lane], l[j]);
    }
    #pragma unroll
    for (int j = 0; j < 8; ++j) lg[wid][j*64 + lane] = l[j];

    // softmax / argmax / loss (wave-local)
    float m = l[0]; int mi = lane;
    #pragma unroll
    for (int j = 1; j < 8; ++j)
        if (l[j] > m) { m = l[j]; mi = j*64 + lane; }
    #pragma unroll
    for (int o = 32; o > 0; o >>= 1) {
        float om = __shfl_down(m, o, 64);
        int   oi = __shfl_down(mi, o, 64);
        if (om > m || (om == m && oi < mi)) { m = om; mi = oi; }
    }
    float maxv = __shfl(m, 0, 64);
    int   maxi = __shfl(mi, 0, 64);
    float es = 0.f;
    #pragma unroll
    for (int j = 0; j < 8; ++j) es += __expf(l[j] - maxv);
    float sum = wred_sum(es);
    if (lane == 0) {
        int target = ncode[(n*3 + sn)*512 + vox];
        float logp = lg[wid][target] - maxv - __logf(sum);
        lsum[wid] = -logp * (1.f/3072.f);
        out[1572865 + (n*3 + sn)*512 + vox] = (float)maxi;
    }

    __syncthreads();
    if (t == 0) lossb[blk] = lsum[0] + lsum[1] + lsum[2] + lsum[3];
    for (int co = t; co < 512; co += 256) {
        float4 o4 = { lg[0][co], lg[1][co], lg[2][co], lg[3][co] };
        *(float4*)(out + (size_t)((n*512 + co)*3 + sn)*512 + vox0) = o4;
    }
}

__global__ void loss_fin_kernel(const float* __restrict__ lossb,
                                float* __restrict__ out)
{
    float s = 0.f;
    for (int i = threadIdx.x; i < 768; i += 64) s += lossb[i];
    s = wred_sum(s);
    if (threadIdx.x == 0) out[1572864] = s;
}

extern "C" void kernel_launch(void* const* d_in, const int* in_sizes, int n_in,
                              void* d_out, int out_size, void* d_ws, size_t ws_size,
                              hipStream_t stream) {
    (void)in_sizes; (void)n_in; (void)out_size; (void)ws_size;
    const int*   code  = (const int*)d_in[0];
    const int*   ncode = (const int*)d_in[1];
    const float* emb   = (const float*)d_in[2];
    const float* win   = (const float*)d_in[3];
    const float* bin_  = (const float*)d_in[4];
    const float* gin_w = (const float*)d_in[5];
    const float* gin_b = (const float*)d_in[6];
    const float* wh    = (const float*)d_in[7];
    const float* bh    = (const float*)d_in[8];
    const float* gh_w  = (const float*)d_in[9];
    const float* gh_b  = (const float*)d_in[10];
    const float* w1    = (const float*)d_in[11];
    const float* b1    = (const float*)d_in[12];
    const float* ln_g  = (const float*)d_in[13];
    const float* ln_b  = (const float*)d_in[14];
    const float* w2    = (const float*)d_in[15];
    const float* b2    = (const float*)d_in[16];
    float* out = (float*)d_out;

    float* base  = (float*)d_ws;
    f16*   wp    = (f16*)base;                    // 1,769,472 floats
    f16*   emb16 = (f16*)(base + 1769472);        // 32,768 floats
    f16*   h1    = (f16*)(base + 1802240);        // 458,752 floats
    f16*   h2    = (f16*)(base + 2260992);        // 458,752 floats
    float* gi1   = base + 2719744;                // 7 slots x 2 partials
    float* gi2   = gi1 + 7*2*(size_t)GPART;       // base + 6,389,760
    float* ghat1 = gi2 + 2*GPART;                 // base + 6,914,048
    float* ghat2 = ghat1 + 2*GPART;               // base + 7,438,336
    float* cx1   = ghat2 + 2*GPART;               // base + 7,962,624
    float* cx2   = cx1 + 65536;                   // base + 8,028,160
    float* lossb = base + 8093696;                // 768 floats

    const f16* win0 = wp;
    const f16* wh0  = wp + WPT;
    const f16* win1 = wp + 2*WPT;
    const f16* wh1  = wp + 3*WPT;

    prep_kernel<<<236, 256, 0, stream>>>(emb, emb16, win, wh, wp);

    // all 7 recurrence-free layer-1 input convs, one batched dispatch
    // (x gathered straight from emb16 via code/ncode tokens)
    {
        MJobs js{};
        for (int s = 0; s < 7; ++s) {
            MJob j;
            j.x = emb16; j.w = win0; j.y = gi1 + (size_t)s*2*GPART;
            if (s < 5) { j.toks = code + s*512;        j.tokStride = 5*512; }
            else       { j.toks = ncode + (s-5)*512;   j.tokStride = 3*512; }
            js.j[s] = j;
        }
        conv_mfma_kernel<<<dim3(256, 7), 256, 0, stream>>>(js);
    }

    for (int s = 0; s <= 6; ++s) {
        // ---- gates: gates1(s); gates2(s-1) if s>=1 ----
        GJob g1 = { gi1 + (size_t)s*2*GPART, gi1 + (size_t)s*2*GPART + GPART,
                    ghat1, ghat1 + GPART, bin_, bh,
                    gin_w, gin_b, gh_w, gh_b, cx1, h1, s, s == 0 };
        GJob g2 = { gi2, gi2 + GPART, ghat2, ghat2 + GPART, bin_ + 256, bh + 256,
                    gin_w + 256, gin_b + 256, gh_w + 256, gh_b + 256,
                    cx2, h2, s - 1, s == 1 };
        if (s == 0)
            gates_step_kernel<<<dim3(256, 1), 256, 0, stream>>>(g1, g1);
        else
            gates_step_kernel<<<dim3(256, 2), 256, 0, stream>>>(g1, g2);

        // ---- convs: rec1(s) [s<=5], in2(s), rec2(s-1) [s>=1] ----
        MJobs js{}; int nj = 0;
        if (s <= 5) js.j[nj++] = { h1 + (size_t)s*XSP,     wh0,  ghat1, nullptr, 0 };
        js.j[nj++]             = { h1 + (size_t)s*XSP,     win1, gi2,   nullptr, 0 };
        if (s >= 1) js.j[nj++] = { h2 + (size_t)(s-1)*XSP, wh1,  ghat2, nullptr, 0 };
        conv_mfma_kernel<<<dim3(256, nj), 256, 0, stream>>>(js);
    }

    // head absorbs gates2(6) for sn==2 blocks
    GJob g2h = { gi2, gi2 + GPART, ghat2, ghat2 + GPART, bin_ + 256, bh + 256,
                 gin_w + 256, gin_b + 256, gh_w + 256, gh_b + 256,
                 cx2, h2, 6, 0 };
    head_kernel<<<768, 256, 0, stream>>>(h2, w1, b1, ln_g, ln_b, w2, b2,
                                         ncode, out, lossb, g2h);
    loss_fin_kernel<<<1, 64, 0, stream>>>(lossb, out);
}